// Round 10
// baseline (182.147 us; speedup 1.0000x reference)
//
#include <hip/hip_runtime.h>
#include <hip/hip_bf16.h>

#define N_NODES 100000
#define N_EDGES 1600000
#define IN_DIM 128
#define HID 64
#define OUT_DIM 32
#define LN_EPS 1e-5f
#define NBKT 782            // ceil(100000/128) coarse buckets (128 nodes each)
#define NPBLK 500           // partition blocks
#define PAIRS_PER_BLK 1600  // 500*1600*2 = 1.6M edges
#define G0T 1563            // gemm0 row-tiles: ceil(100000/64)
#define PADCAP 384          // max padding per bucket (128 nodes * 3)

typedef __attribute__((ext_vector_type(8))) _Float16 half8;
typedef __attribute__((ext_vector_type(4))) float f32x4;

__device__ __forceinline__ float uflo(unsigned int u) {
  return __uint_as_float(u << 16);
}
__device__ __forceinline__ float ufhi(unsigned int u) {
  return __uint_as_float(u & 0xffff0000u);
}
__device__ __forceinline__ unsigned short bf16rne(float f) {
  unsigned int u = __float_as_uint(f);
  unsigned int r = u + 0x7fffu + ((u >> 16) & 1u);
  return (unsigned short)(r >> 16);
}

// ---------- Edge dtype detect: int64 (high words all 0) vs int32 ------------
__global__ void detect_edges(const int* __restrict__ w, int* __restrict__ flag) {
  __shared__ int any;
  if (threadIdx.x == 0) any = 0;
  __syncthreads();
  if (w[2 * threadIdx.x + 1] != 0) any = 1;
  __syncthreads();
  if (threadIdx.x == 0) flag[0] = any ? 0 : 1;  // 1 => int64 layout
}

// ---------- Weight convert to fp16: B0 [128n][128k], B1 [64n][64k] ----------
__global__ __launch_bounds__(256) void convW(
    const float* __restrict__ Wn0, const float* __restrict__ Ws0,
    const float* __restrict__ Wn1, const float* __restrict__ Ws1,
    _Float16* __restrict__ B0f, _Float16* __restrict__ B1f) {
  const int i = blockIdx.x * 256 + threadIdx.x;
  if (i < 128 * 128) {
    const int n = i >> 7, k = i & 127;
    const float w = (n < 64) ? Wn0[k * 64 + n] : Ws0[k * 64 + (n - 64)];
    B0f[i] = (_Float16)w;
  } else if (i < 128 * 128 + 64 * 64) {
    const int j = i - 128 * 128;
    const int n = j >> 6, k = j & 63;
    const float w = (n < 32) ? Wn1[k * 32 + n] : Ws1[k * 32 + (n - 32)];
    B1f[j] = (_Float16)w;
  }
}

// ---------- FUSED: part_count (blocks 0..499) || gemm0 (blocks 500..3625) ---
// gemm0 split into 2 column-groups of 64: colgrp 0 -> p0u, colgrp 1 -> s0b.
__global__ __launch_bounds__(256) void g0pc(
    const float* __restrict__ x, const _Float16* __restrict__ B0f,
    const float* __restrict__ b0,
    unsigned short* __restrict__ p0u, float* __restrict__ s0b,
    const int* __restrict__ w, const int* __restrict__ flag,
    int* __restrict__ gcount, int* __restrict__ blkbase) {
  __shared__ _Float16 lb[64 * 128];  // 16 KB (pc path: int hist scratch)
  const int tid = threadIdx.x;

  if (blockIdx.x < NPBLK) {
    // ---------------- part_count path ----------------
    int* h = (int*)lb;
    const int b = blockIdx.x;
    for (int i = tid; i < NBKT; i += 256) h[i] = 0;
    __syncthreads();
    const int i64 = flag[0];
    const int pEnd = (b + 1) * PAIRS_PER_BLK;
    for (int p = b * PAIRS_PER_BLK + tid; p < pEnd; p += 256) {
      int d0, d1;
      if (i64) {
        const int4 vd = *(const int4*)(w + 2 * (size_t)N_EDGES + 4 * (size_t)p);
        d0 = vd.x; d1 = vd.z;
      } else {
        const int2 vd = *(const int2*)(w + (size_t)N_EDGES + 2 * (size_t)p);
        d0 = vd.x; d1 = vd.y;
      }
      atomicAdd(&h[d0 >> 7], 1);
      atomicAdd(&h[d1 >> 7], 1);
    }
    __syncthreads();
    for (int i = tid; i < NBKT; i += 256)
      blkbase[b * NBKT + i] = atomicAdd(&gcount[i], h[i]);  // coalesced
    return;
  }

  // ---------------- gemm0 path (64 rows x 64 cols per block) ----------------
  const int gb = blockIdx.x - NPBLK;
  const int colgrp = (gb >= G0T) ? 1 : 0;
  const int rowblk = colgrp ? (gb - G0T) : gb;
  {
    const uint4* gsrc = (const uint4*)(B0f + (colgrp << 13));  // 64*128 halfs
    for (int i = tid; i < 1024; i += 256) {
      const int o = i << 4;
      const int sw = o ^ (((o >> 8) & 7) << 4);
      *(uint4*)((char*)lb + sw) = gsrc[i];
    }
  }
  __syncthreads();
  const int lane = tid & 63;
  const int wave = tid >> 6;
  const int rowbase = rowblk * 64 + wave * 16;
  const int arow = rowbase + (lane & 15);
  const int rclamp = (arow < N_NODES) ? arow : 0;
  const int ko = (lane >> 4) << 3;  // 0,8,16,24

  f32x4 acc[4];
#pragma unroll
  for (int ct = 0; ct < 4; ++ct) acc[ct] = (f32x4){0.f, 0.f, 0.f, 0.f};

  for (int ks = 0; ks < 4; ++ks) {
    float av[8];
    const float* ax = x + (size_t)rclamp * IN_DIM + ks * 32 + ko;
    *(float4*)&av[0] = *(const float4*)ax;
    *(float4*)&av[4] = *(const float4*)(ax + 4);
    half8 ah;
#pragma unroll
    for (int j = 0; j < 8; ++j) ah[j] = (_Float16)av[j];
    const int kb = ks * 64 + (ko << 1);
#pragma unroll
    for (int ct = 0; ct < 4; ++ct) {
      const int n = ct * 16 + (lane & 15);
      const int boff = (n << 8) + kb;
      const int sb = boff ^ (((boff >> 8) & 7) << 4);
      const half8 bv = *(const half8*)((const char*)lb + sb);
      acc[ct] = __builtin_amdgcn_mfma_f32_16x16x32_f16(ah, bv, acc[ct], 0, 0, 0);
    }
  }
  const int rb4 = rowbase + ((lane >> 4) << 2);
  const int cc = lane & 15;
  if (colgrp == 0) {  // -> p0u (bf16)
#pragma unroll
    for (int ct = 0; ct < 4; ++ct) {
#pragma unroll
      for (int j = 0; j < 4; ++j) {
        const int r = rb4 + j;
        if (r < N_NODES) p0u[(size_t)r * HID + ct * 16 + cc] = bf16rne(acc[ct][j]);
      }
    }
  } else {  // -> s0b (fp32 + bias)
#pragma unroll
    for (int ct = 0; ct < 4; ++ct) {
      const float bias = b0[ct * 16 + cc];
#pragma unroll
      for (int j = 0; j < 4; ++j) {
        const int r = rb4 + j;
        if (r < N_NODES) s0b[(size_t)r * HID + ct * 16 + cc] = acc[ct][j] + bias;
      }
    }
  }
}

// ---------- Phase B: single-block exclusive scan of 782 bucket counts -------
__global__ __launch_bounds__(256) void part_scan(
    const int* __restrict__ gcount, int* __restrict__ gbase) {
  __shared__ int lds[256];
  const int t = threadIdx.x;
  int v[4];
  int s = 0;
#pragma unroll
  for (int j = 0; j < 4; ++j) {
    const int idx = t * 4 + j;
    v[j] = (idx < NBKT) ? gcount[idx] : 0;
    s += v[j];
  }
  lds[t] = s;
  __syncthreads();
  for (int o = 1; o < 256; o <<= 1) {
    const int val = (t >= o) ? lds[t - o] : 0;
    __syncthreads();
    lds[t] += val;
    __syncthreads();
  }
  int run = lds[t] - s;
#pragma unroll
  for (int j = 0; j < 4; ++j) {
    const int idx = t * 4 + j;
    if (idx < NBKT) gbase[idx] = run;
    run += v[j];
  }
}

// ---------- Phase C: scatter packed edges into coarse-bucket regions --------
// pe[e] = src | (localdst << 17)   (src < 2^17, localdst < 128)
__global__ __launch_bounds__(256) void part_scatter(
    const int* __restrict__ w, const int* __restrict__ flag,
    const int* __restrict__ gbase, const int* __restrict__ blkbase,
    int* __restrict__ pe) {
  __shared__ int cur[NBKT];
  const int t = threadIdx.x, b = blockIdx.x;
  for (int i = t; i < NBKT; i += 256)
    cur[i] = gbase[i] + blkbase[b * NBKT + i];
  __syncthreads();
  const int i64 = flag[0];
  const int pEnd = (b + 1) * PAIRS_PER_BLK;
  for (int p = b * PAIRS_PER_BLK + t; p < pEnd; p += 256) {
    int s0, s1, d0, d1;
    if (i64) {
      const int4 vs = *(const int4*)(w + 4 * (size_t)p);
      const int4 vd = *(const int4*)(w + 2 * (size_t)N_EDGES + 4 * (size_t)p);
      s0 = vs.x; s1 = vs.z;
      d0 = vd.x; d1 = vd.z;
    } else {
      const int2 vs = *(const int2*)(w + 2 * (size_t)p);
      const int2 vd = *(const int2*)(w + (size_t)N_EDGES + 2 * (size_t)p);
      s0 = vs.x; s1 = vs.y;
      d0 = vd.x; d1 = vd.y;
    }
    const int sl0 = atomicAdd(&cur[d0 >> 7], 1);
    pe[sl0] = s0 | ((d0 & 127) << 17);
    const int sl1 = atomicAdd(&cur[d1 >> 7], 1);
    pe[sl1] = s1 | ((d1 & 127) << 17);
  }
}

// ---------- Phase D: per-bucket CSR build, padded to x4 with zero-row -------
__global__ __launch_bounds__(256) void bucket_csr(
    const int* __restrict__ pe, const int* __restrict__ gbase,
    const int* __restrict__ gcount, int* __restrict__ deg,
    int* __restrict__ off, int* __restrict__ sortedSrc) {
  __shared__ int ldeg[128];
  __shared__ int loff[128];
  __shared__ int lcur[128];
  const int t = threadIdx.x;
  const int bkt = blockIdx.x;
  const int nbase = bkt << 7;
  const int ebase = gbase[bkt];
  const int cnt = gcount[bkt];
  const int outbase = ebase + PADCAP * bkt;
  if (t < 128) ldeg[t] = 0;
  __syncthreads();
  for (int e = t; e < cnt; e += 256) {
    const int pv = pe[ebase + e];
    atomicAdd(&ldeg[(pv >> 17) & 127], 1);
  }
  __syncthreads();
  if (t < 128) loff[t] = (ldeg[t] + 3) & ~3;  // padded degree
  __syncthreads();
  for (int o = 1; o < 128; o <<= 1) {
    int v = 0;
    if (t >= o && t < 128) v = loff[t - o];
    __syncthreads();
    if (t < 128) loff[t] += v;
    __syncthreads();
  }
  if (t < 128) {
    const int pdeg = (ldeg[t] + 3) & ~3;
    const int ex = loff[t] - pdeg;
    lcur[t] = ex;
    const int n = nbase + t;
    if (n < N_NODES) {
      deg[n] = ldeg[t];
      off[n] = outbase + ex;
    }
  }
  __syncthreads();
  for (int e = t; e < cnt; e += 256) {
    const int pv = pe[ebase + e];
    const int ld = (pv >> 17) & 127;
    const int p = atomicAdd(&lcur[ld], 1);
    sortedSrc[outbase + p] = pv & 0x1FFFF;
  }
  __syncthreads();
  if (t < 128) {
    const int pdeg = (ldeg[t] + 3) & ~3;
    const int ex = loff[t] - pdeg;
    for (int q = ldeg[t]; q < pdeg; ++q)
      sortedSrc[outbase + ex + q] = N_NODES;  // zero row
  }
}

// ------- Layer 1 fp16 MFMA GEMM: [p1 | s1b] = h1 @ [Wneigh1 | Wself1] (+b1) -
__global__ __launch_bounds__(256) void gemm1(
    const float* __restrict__ h1, const _Float16* __restrict__ B1f,
    const float* __restrict__ b1,
    unsigned short* __restrict__ p1u, float* __restrict__ s1b) {
  __shared__ _Float16 lb[64 * 64];  // 8 KB
  const int tid = threadIdx.x;
  {
    const uint4* gb = (const uint4*)B1f;
    for (int i = tid; i < 512; i += 256) {
      const int o = i << 4;
      const int sw = o ^ (((o >> 7) & 7) << 4);
      *(uint4*)((char*)lb + sw) = gb[i];
    }
  }
  __syncthreads();
  const int lane = tid & 63;
  const int wave = tid >> 6;
  const int rowbase = blockIdx.x * 64 + wave * 16;
  const int arow = rowbase + (lane & 15);
  const int rclamp = (arow < N_NODES) ? arow : 0;
  const int ko = (lane >> 4) << 3;

  f32x4 acc[4];
#pragma unroll
  for (int ct = 0; ct < 4; ++ct) acc[ct] = (f32x4){0.f, 0.f, 0.f, 0.f};

  for (int ks = 0; ks < 2; ++ks) {
    float av[8];
    const float* ax = h1 + (size_t)rclamp * HID + ks * 32 + ko;
    *(float4*)&av[0] = *(const float4*)ax;
    *(float4*)&av[4] = *(const float4*)(ax + 4);
    half8 ah;
#pragma unroll
    for (int j = 0; j < 8; ++j) ah[j] = (_Float16)av[j];
    const int kb = ks * 64 + (ko << 1);
#pragma unroll
    for (int ct = 0; ct < 4; ++ct) {
      const int n = ct * 16 + (lane & 15);
      const int boff = (n << 7) + kb;
      const int sb = boff ^ (((boff >> 7) & 7) << 4);
      const half8 bv = *(const half8*)((const char*)lb + sb);
      acc[ct] = __builtin_amdgcn_mfma_f32_16x16x32_f16(ah, bv, acc[ct], 0, 0, 0);
    }
  }
  const int rb4 = rowbase + ((lane >> 4) << 2);
  const int cc = lane & 15;
#pragma unroll
  for (int ct = 0; ct < 2; ++ct) {  // -> p1 (bf16)
#pragma unroll
    for (int j = 0; j < 4; ++j) {
      const int r = rb4 + j;
      if (r < N_NODES) p1u[(size_t)r * OUT_DIM + ct * 16 + cc] = bf16rne(acc[ct][j]);
    }
  }
#pragma unroll
  for (int ct = 2; ct < 4; ++ct) {  // -> s1b (fp32 + bias)
    const float bias = b1[(ct - 2) * 16 + cc];
#pragma unroll
    for (int j = 0; j < 4; ++j) {
      const int r = rb4 + j;
      if (r < N_NODES)
        s1b[(size_t)r * OUT_DIM + (ct - 2) * 16 + cc] = acc[ct][j] + bias;
    }
  }
}

// ------- Fused layer-0 aggregate + mean + LN + ReLU -> h1 (2 nodes/wave) ----
// Maskless: edge lists padded to x4 with zero-row (index N_NODES).
__global__ __launch_bounds__(256) void aggc0(
    const int* __restrict__ sortedSrc, const int* __restrict__ off,
    const int* __restrict__ deg, const unsigned short* __restrict__ p0u,
    const float* __restrict__ s0b, const float* __restrict__ g,
    const float* __restrict__ be, float* __restrict__ h1) {
  const int lane = threadIdx.x & 63;
  const int h = lane >> 5;          // node half
  const int grp = (lane >> 3) & 3;  // 4 edge groups
  const int sl = lane & 7;          // 8 feature slices
  const int i = blockIdx.x * 8 + ((threadIdx.x >> 6) << 1) + h;
  const int st = off[i];
  const int dg = deg[i];
  const int dgp = (dg + 3) & ~3;
  const int dgmaxp = max(dgp, __shfl_xor(dgp, 32));
  float acc[8];
#pragma unroll
  for (int f = 0; f < 8; ++f) acc[f] = 0.f;

  for (int base = 0; base < dgmaxp; base += 32) {
    const int cntp = dgp - base;
    const int l5 = lane & 31;
    const int idx = (l5 < cntp) ? sortedSrc[st + base + l5] : N_NODES;
    const int cm = min(32, dgmaxp - base);  // multiple of 4
    for (int j = 0; j * 4 < cm; ++j) {
      const int e = j * 4 + grp;
      const int srcn = __shfl(idx, (h << 5) | e);
      const uint4 q = *(const uint4*)(p0u + (size_t)srcn * HID + sl * 8);
      acc[0] += uflo(q.x); acc[1] += ufhi(q.x);
      acc[2] += uflo(q.y); acc[3] += ufhi(q.y);
      acc[4] += uflo(q.z); acc[5] += ufhi(q.z);
      acc[6] += uflo(q.w); acc[7] += ufhi(q.w);
    }
  }
  // fold edge groups (xor over lane bits 3,4 — stays within node half)
#pragma unroll
  for (int mk = 8; mk < 32; mk <<= 1) {
#pragma unroll
    for (int f = 0; f < 8; ++f) acc[f] += __shfl_xor(acc[f], mk);
  }
  const float inv = 1.0f / fmaxf((float)dg, 1.0f);
  float z[8];
  const float4 sb0 = *(const float4*)(s0b + (size_t)i * HID + sl * 8);
  const float4 sb1 = *(const float4*)(s0b + (size_t)i * HID + sl * 8 + 4);
  z[0] = sb0.x + acc[0] * inv; z[1] = sb0.y + acc[1] * inv;
  z[2] = sb0.z + acc[2] * inv; z[3] = sb0.w + acc[3] * inv;
  z[4] = sb1.x + acc[4] * inv; z[5] = sb1.y + acc[5] * inv;
  z[6] = sb1.z + acc[6] * inv; z[7] = sb1.w + acc[7] * inv;
  float pm = 0.f;
#pragma unroll
  for (int f = 0; f < 8; ++f) pm += z[f];
#pragma unroll
  for (int mk = 1; mk < 8; mk <<= 1) pm += __shfl_xor(pm, mk);
  const float mean = pm * (1.0f / 64.0f);
  float pv = 0.f;
#pragma unroll
  for (int f = 0; f < 8; ++f) {
    z[f] -= mean;
    pv += z[f] * z[f];
  }
#pragma unroll
  for (int mk = 1; mk < 8; mk <<= 1) pv += __shfl_xor(pv, mk);
  const float rstd = rsqrtf(pv * (1.0f / 64.0f) + LN_EPS);
  if (grp == 0) {
    const float4 gv0 = *(const float4*)(g + sl * 8);
    const float4 gv1 = *(const float4*)(g + sl * 8 + 4);
    const float4 bv0 = *(const float4*)(be + sl * 8);
    const float4 bv1 = *(const float4*)(be + sl * 8 + 4);
    float4 o0, o1;
    o0.x = fmaxf(z[0] * rstd * gv0.x + bv0.x, 0.f);
    o0.y = fmaxf(z[1] * rstd * gv0.y + bv0.y, 0.f);
    o0.z = fmaxf(z[2] * rstd * gv0.z + bv0.z, 0.f);
    o0.w = fmaxf(z[3] * rstd * gv0.w + bv0.w, 0.f);
    o1.x = fmaxf(z[4] * rstd * gv1.x + bv1.x, 0.f);
    o1.y = fmaxf(z[5] * rstd * gv1.y + bv1.y, 0.f);
    o1.z = fmaxf(z[6] * rstd * gv1.z + bv1.z, 0.f);
    o1.w = fmaxf(z[7] * rstd * gv1.w + bv1.w, 0.f);
    *(float4*)(h1 + (size_t)i * HID + sl * 8) = o0;
    *(float4*)(h1 + (size_t)i * HID + sl * 8 + 4) = o1;
  }
}

// ------- Fused layer-1 aggregate + mean + LN + ReLU -> out (4 nodes/wave) ---
__global__ __launch_bounds__(256) void aggc1(
    const int* __restrict__ sortedSrc, const int* __restrict__ off,
    const int* __restrict__ deg, const unsigned short* __restrict__ p1u,
    const float* __restrict__ s1b, const float* __restrict__ g,
    const float* __restrict__ be, float* __restrict__ out) {
  const int lane = threadIdx.x & 63;
  const int q4 = lane >> 4;         // node quarter
  const int grp = (lane >> 2) & 3;  // 4 edge groups
  const int sl = lane & 3;          // 4 feature slices
  const int i = blockIdx.x * 16 + ((threadIdx.x >> 6) << 2) + q4;
  const int st = off[i];
  const int dg = deg[i];
  const int dgp = (dg + 3) & ~3;
  int dm = max(dgp, __shfl_xor(dgp, 16));
  const int dgmaxp = max(dm, __shfl_xor(dm, 32));
  float acc[8];
#pragma unroll
  for (int f = 0; f < 8; ++f) acc[f] = 0.f;

  for (int base = 0; base < dgmaxp; base += 16) {
    const int cntp = dgp - base;
    const int l4 = lane & 15;
    const int idx = (l4 < cntp) ? sortedSrc[st + base + l4] : N_NODES;
    const int cm = min(16, dgmaxp - base);  // multiple of 4
    for (int j = 0; j * 4 < cm; ++j) {
      const int e = j * 4 + grp;
      const int srcn = __shfl(idx, (q4 << 4) | e);
      const uint4 qv = *(const uint4*)(p1u + (size_t)srcn * OUT_DIM + sl * 8);
      acc[0] += uflo(qv.x); acc[1] += ufhi(qv.x);
      acc[2] += uflo(qv.y); acc[3] += ufhi(qv.y);
      acc[4] += uflo(qv.z); acc[5] += ufhi(qv.z);
      acc[6] += uflo(qv.w); acc[7] += ufhi(qv.w);
    }
  }
  // fold edge groups (xor over lane bits 2,3 — stays within node quarter)
#pragma unroll
  for (int mk = 4; mk < 16; mk <<= 1) {
#pragma unroll
    for (int f = 0; f < 8; ++f) acc[f] += __shfl_xor(acc[f], mk);
  }
  const float inv = 1.0f / fmaxf((float)dg, 1.0f);
  float z[8];
  const float4 sb0 = *(const float4*)(s1b + (size_t)i * OUT_DIM + sl * 8);
  const float4 sb1 = *(const float4*)(s1b + (size_t)i * OUT_DIM + sl * 8 + 4);
  z[0] = sb0.x + acc[0] * inv; z[1] = sb0.y + acc[1] * inv;
  z[2] = sb0.z + acc[2] * inv; z[3] = sb0.w + acc[3] * inv;
  z[4] = sb1.x + acc[4] * inv; z[5] = sb1.y + acc[5] * inv;
  z[6] = sb1.z + acc[6] * inv; z[7] = sb1.w + acc[7] * inv;
  float pm = 0.f;
#pragma unroll
  for (int f = 0; f < 8; ++f) pm += z[f];
#pragma unroll
  for (int mk = 1; mk < 4; mk <<= 1) pm += __shfl_xor(pm, mk);
  const float mean = pm * (1.0f / 32.0f);
  float pv = 0.f;
#pragma unroll
  for (int f = 0; f < 8; ++f) {
    z[f] -= mean;
    pv += z[f] * z[f];
  }
#pragma unroll
  for (int mk = 1; mk < 4; mk <<= 1) pv += __shfl_xor(pv, mk);
  const float rstd = rsqrtf(pv * (1.0f / 32.0f) + LN_EPS);
  if (grp == 0) {
    const float4 gv0 = *(const float4*)(g + sl * 8);
    const float4 gv1 = *(const float4*)(g + sl * 8 + 4);
    const float4 bv0 = *(const float4*)(be + sl * 8);
    const float4 bv1 = *(const float4*)(be + sl * 8 + 4);
    float4 o0, o1;
    o0.x = fmaxf(z[0] * rstd * gv0.x + bv0.x, 0.f);
    o0.y = fmaxf(z[1] * rstd * gv0.y + bv0.y, 0.f);
    o0.z = fmaxf(z[2] * rstd * gv0.z + bv0.z, 0.f);
    o0.w = fmaxf(z[3] * rstd * gv0.w + bv0.w, 0.f);
    o1.x = fmaxf(z[4] * rstd * gv1.x + bv1.x, 0.f);
    o1.y = fmaxf(z[5] * rstd * gv1.y + bv1.y, 0.f);
    o1.z = fmaxf(z[6] * rstd * gv1.z + bv1.z, 0.f);
    o1.w = fmaxf(z[7] * rstd * gv1.w + bv1.w, 0.f);
    *(float4*)(out + (size_t)i * OUT_DIM + sl * 8) = o0;
    *(float4*)(out + (size_t)i * OUT_DIM + sl * 8 + 4) = o1;
  }
}

extern "C" void kernel_launch(void* const* d_in, const int* in_sizes, int n_in,
                              void* d_out, int out_size, void* d_ws, size_t ws_size,
                              hipStream_t stream) {
  const float* x       = (const float*)d_in[0];
  const int*   edges   = (const int*)d_in[1];
  const float* Wself0  = (const float*)d_in[2];
  const float* Wneigh0 = (const float*)d_in[3];
  const float* b0      = (const float*)d_in[4];
  const float* g0      = (const float*)d_in[5];
  const float* be0     = (const float*)d_in[6];
  const float* Wself1  = (const float*)d_in[7];
  const float* Wneigh1 = (const float*)d_in[8];
  const float* b1      = (const float*)d_in[9];
  const float* g1      = (const float*)d_in[10];
  const float* be1     = (const float*)d_in[11];

  int* flag      = (int*)d_ws;                    // 64
  int* gcount    = flag + 64;                     // 1024 (padded)
  int* gbase     = gcount + 1024;                 // 1024 (padded)
  int* blkbase   = gbase + 1024;                  // NPBLK*NBKT = 391000
  int* deg       = blkbase + 400000;              // 100000
  int* off       = deg + N_NODES;                 // 100000
  int* sortedSrc = off + N_NODES;                 // 1.6M + 384*782 (padded)
  int* pe        = sortedSrc + 1950000;           // 1.62M ints (packed edges)
  _Float16* B0f  = (_Float16*)(pe + 1620000);     // 16384 halfs
  _Float16* B1f  = B0f + 128 * 128;               // 4096 halfs
  unsigned short* p0u = (unsigned short*)(B1f + 64 * 64);  // (N+1)*64 bf16
  float* s0b = (float*)(p0u + ((size_t)N_NODES + 1) * HID);
  float* h1  = s0b + (size_t)N_NODES * HID;
  unsigned short* p1u = (unsigned short*)pe;  // overlay (pe dead after csr)
  float* s1b = s0b;                           // overlay (s0b dead after aggc0)

  hipMemsetAsync(gcount, 0, NBKT * sizeof(int), stream);
  hipMemsetAsync(p0u + (size_t)N_NODES * HID, 0, HID * sizeof(unsigned short),
                 stream);  // zero row for aggc0

  detect_edges<<<1, 256, 0, stream>>>(edges, flag);
  convW<<<80, 256, 0, stream>>>(Wneigh0, Wself0, Wneigh1, Wself1, B0f, B1f);
  g0pc<<<NPBLK + 2 * G0T, 256, 0, stream>>>(x, B0f, b0, p0u, s0b,
                                            edges, flag, gcount, blkbase);
  part_scan<<<1, 256, 0, stream>>>(gcount, gbase);
  part_scatter<<<NPBLK, 256, 0, stream>>>(edges, flag, gbase, blkbase, pe);
  bucket_csr<<<NBKT, 256, 0, stream>>>(pe, gbase, gcount, deg, off, sortedSrc);

  // pe is dead now; zero p1u's zero-row (inside old pe region) before aggc1
  hipMemsetAsync(p1u + (size_t)N_NODES * OUT_DIM, 0,
                 OUT_DIM * sizeof(unsigned short), stream);

  aggc0<<<N_NODES / 8, 256, 0, stream>>>(sortedSrc, off, deg, p0u, s0b,
                                         g0, be0, h1);
  gemm1<<<(N_NODES + 63) / 64, 256, 0, stream>>>(h1, B1f, b1, p1u, s1b);
  aggc1<<<N_NODES / 16, 256, 0, stream>>>(sortedSrc, off, deg, p1u, s1b,
                                          g1, be1, (float*)d_out);
}

// Round 11
// 166.120 us; speedup vs baseline: 1.0965x; 1.0965x over previous
//
#include <hip/hip_runtime.h>
#include <hip/hip_bf16.h>

#define N_NODES 100000
#define N_EDGES 1600000
#define IN_DIM 128
#define HID 64
#define OUT_DIM 32
#define LN_EPS 1e-5f
#define NBKT 782            // ceil(100000/128) coarse buckets (128 nodes each)
#define NPBLK 500           // partition blocks
#define PAIRS_PER_BLK 1600  // 500*1600*2 = 1.6M edges
#define G0T 1563            // gemm0 row-tiles: ceil(100000/64)
#define PADCAP 384          // max padding per bucket (128 nodes * 3)

typedef __attribute__((ext_vector_type(8))) _Float16 half8;
typedef __attribute__((ext_vector_type(4))) float f32x4;

__device__ __forceinline__ float uflo(unsigned int u) {
  return __uint_as_float(u << 16);
}
__device__ __forceinline__ float ufhi(unsigned int u) {
  return __uint_as_float(u & 0xffff0000u);
}
__device__ __forceinline__ unsigned short bf16rne(float f) {
  unsigned int u = __float_as_uint(f);
  unsigned int r = u + 0x7fffu + ((u >> 16) & 1u);
  return (unsigned short)(r >> 16);
}

// ---------- Edge dtype detect: int64 (high words all 0) vs int32 ------------
__global__ void detect_edges(const int* __restrict__ w, int* __restrict__ flag) {
  __shared__ int any;
  if (threadIdx.x == 0) any = 0;
  __syncthreads();
  if (w[2 * threadIdx.x + 1] != 0) any = 1;
  __syncthreads();
  if (threadIdx.x == 0) flag[0] = any ? 0 : 1;  // 1 => int64 layout
}

// ---------- Weight convert to fp16: B0 [128n][128k], B1 [64n][64k] ----------
__global__ __launch_bounds__(256) void convW(
    const float* __restrict__ Wn0, const float* __restrict__ Ws0,
    const float* __restrict__ Wn1, const float* __restrict__ Ws1,
    _Float16* __restrict__ B0f, _Float16* __restrict__ B1f) {
  const int i = blockIdx.x * 256 + threadIdx.x;
  if (i < 128 * 128) {
    const int n = i >> 7, k = i & 127;
    const float w = (n < 64) ? Wn0[k * 64 + n] : Ws0[k * 64 + (n - 64)];
    B0f[i] = (_Float16)w;
  } else if (i < 128 * 128 + 64 * 64) {
    const int j = i - 128 * 128;
    const int n = j >> 6, k = j & 63;
    const float w = (n < 32) ? Wn1[k * 32 + n] : Ws1[k * 32 + (n - 32)];
    B1f[j] = (_Float16)w;
  }
}

// ---------- FUSED: part_count (blocks 0..499) || gemm0 (blocks 500..3625) ---
// gemm0 split into 2 column-groups of 64: colgrp 0 -> p0u, colgrp 1 -> s0b.
__global__ __launch_bounds__(256) void g0pc(
    const float* __restrict__ x, const _Float16* __restrict__ B0f,
    const float* __restrict__ b0,
    unsigned short* __restrict__ p0u, float* __restrict__ s0b,
    const int* __restrict__ w, const int* __restrict__ flag,
    int* __restrict__ gcount, int* __restrict__ blkbase) {
  __shared__ _Float16 lb[64 * 128];  // 16 KB (pc path: int hist scratch)
  const int tid = threadIdx.x;

  if (blockIdx.x < NPBLK) {
    // ---------------- part_count path ----------------
    int* h = (int*)lb;
    const int b = blockIdx.x;
    for (int i = tid; i < NBKT; i += 256) h[i] = 0;
    __syncthreads();
    const int i64 = flag[0];
    const int pEnd = (b + 1) * PAIRS_PER_BLK;
    for (int p = b * PAIRS_PER_BLK + tid; p < pEnd; p += 256) {
      int d0, d1;
      if (i64) {
        const int4 vd = *(const int4*)(w + 2 * (size_t)N_EDGES + 4 * (size_t)p);
        d0 = vd.x; d1 = vd.z;
      } else {
        const int2 vd = *(const int2*)(w + (size_t)N_EDGES + 2 * (size_t)p);
        d0 = vd.x; d1 = vd.y;
      }
      atomicAdd(&h[d0 >> 7], 1);
      atomicAdd(&h[d1 >> 7], 1);
    }
    __syncthreads();
    for (int i = tid; i < NBKT; i += 256)
      blkbase[b * NBKT + i] = atomicAdd(&gcount[i], h[i]);  // coalesced
    return;
  }

  // ---------------- gemm0 path (64 rows x 64 cols per block) ----------------
  const int gb = blockIdx.x - NPBLK;
  const int colgrp = (gb >= G0T) ? 1 : 0;
  const int rowblk = colgrp ? (gb - G0T) : gb;
  {
    const uint4* gsrc = (const uint4*)(B0f + (colgrp << 13));  // 64*128 halfs
    for (int i = tid; i < 1024; i += 256) {
      const int o = i << 4;
      const int sw = o ^ (((o >> 8) & 7) << 4);
      *(uint4*)((char*)lb + sw) = gsrc[i];
    }
  }
  __syncthreads();
  const int lane = tid & 63;
  const int wave = tid >> 6;
  const int rowbase = rowblk * 64 + wave * 16;
  const int arow = rowbase + (lane & 15);
  const int rclamp = (arow < N_NODES) ? arow : 0;
  const int ko = (lane >> 4) << 3;  // 0,8,16,24

  f32x4 acc[4];
#pragma unroll
  for (int ct = 0; ct < 4; ++ct) acc[ct] = (f32x4){0.f, 0.f, 0.f, 0.f};

  for (int ks = 0; ks < 4; ++ks) {
    float av[8];
    const float* ax = x + (size_t)rclamp * IN_DIM + ks * 32 + ko;
    *(float4*)&av[0] = *(const float4*)ax;
    *(float4*)&av[4] = *(const float4*)(ax + 4);
    half8 ah;
#pragma unroll
    for (int j = 0; j < 8; ++j) ah[j] = (_Float16)av[j];
    const int kb = ks * 64 + (ko << 1);
#pragma unroll
    for (int ct = 0; ct < 4; ++ct) {
      const int n = ct * 16 + (lane & 15);
      const int boff = (n << 8) + kb;
      const int sb = boff ^ (((boff >> 8) & 7) << 4);
      const half8 bv = *(const half8*)((const char*)lb + sb);
      acc[ct] = __builtin_amdgcn_mfma_f32_16x16x32_f16(ah, bv, acc[ct], 0, 0, 0);
    }
  }
  const int rb4 = rowbase + ((lane >> 4) << 2);
  const int cc = lane & 15;
  if (colgrp == 0) {  // -> p0u (bf16)
#pragma unroll
    for (int ct = 0; ct < 4; ++ct) {
#pragma unroll
      for (int j = 0; j < 4; ++j) {
        const int r = rb4 + j;
        if (r < N_NODES) p0u[(size_t)r * HID + ct * 16 + cc] = bf16rne(acc[ct][j]);
      }
    }
  } else {  // -> s0b (fp32 + bias)
#pragma unroll
    for (int ct = 0; ct < 4; ++ct) {
      const float bias = b0[ct * 16 + cc];
#pragma unroll
      for (int j = 0; j < 4; ++j) {
        const int r = rb4 + j;
        if (r < N_NODES) s0b[(size_t)r * HID + ct * 16 + cc] = acc[ct][j] + bias;
      }
    }
  }
}

// ---------- Phase B: single-block exclusive scan of 782 bucket counts -------
__global__ __launch_bounds__(256) void part_scan(
    const int* __restrict__ gcount, int* __restrict__ gbase) {
  __shared__ int lds[256];
  const int t = threadIdx.x;
  int v[4];
  int s = 0;
#pragma unroll
  for (int j = 0; j < 4; ++j) {
    const int idx = t * 4 + j;
    v[j] = (idx < NBKT) ? gcount[idx] : 0;
    s += v[j];
  }
  lds[t] = s;
  __syncthreads();
  for (int o = 1; o < 256; o <<= 1) {
    const int val = (t >= o) ? lds[t - o] : 0;
    __syncthreads();
    lds[t] += val;
    __syncthreads();
  }
  int run = lds[t] - s;
#pragma unroll
  for (int j = 0; j < 4; ++j) {
    const int idx = t * 4 + j;
    if (idx < NBKT) gbase[idx] = run;
    run += v[j];
  }
}

// ---------- Phase C: scatter packed edges into coarse-bucket regions --------
// pe[e] = src | (localdst << 17)   (src < 2^17, localdst < 128)
__global__ __launch_bounds__(256) void part_scatter(
    const int* __restrict__ w, const int* __restrict__ flag,
    const int* __restrict__ gbase, const int* __restrict__ blkbase,
    int* __restrict__ pe) {
  __shared__ int cur[NBKT];
  const int t = threadIdx.x, b = blockIdx.x;
  for (int i = t; i < NBKT; i += 256)
    cur[i] = gbase[i] + blkbase[b * NBKT + i];
  __syncthreads();
  const int i64 = flag[0];
  const int pEnd = (b + 1) * PAIRS_PER_BLK;
  for (int p = b * PAIRS_PER_BLK + t; p < pEnd; p += 256) {
    int s0, s1, d0, d1;
    if (i64) {
      const int4 vs = *(const int4*)(w + 4 * (size_t)p);
      const int4 vd = *(const int4*)(w + 2 * (size_t)N_EDGES + 4 * (size_t)p);
      s0 = vs.x; s1 = vs.z;
      d0 = vd.x; d1 = vd.z;
    } else {
      const int2 vs = *(const int2*)(w + 2 * (size_t)p);
      const int2 vd = *(const int2*)(w + (size_t)N_EDGES + 2 * (size_t)p);
      s0 = vs.x; s1 = vs.y;
      d0 = vd.x; d1 = vd.y;
    }
    const int sl0 = atomicAdd(&cur[d0 >> 7], 1);
    pe[sl0] = s0 | ((d0 & 127) << 17);
    const int sl1 = atomicAdd(&cur[d1 >> 7], 1);
    pe[sl1] = s1 | ((d1 & 127) << 17);
  }
}

// ---------- Phase D: per-bucket CSR build, padded to x4 with zero-row -------
__global__ __launch_bounds__(256) void bucket_csr(
    const int* __restrict__ pe, const int* __restrict__ gbase,
    const int* __restrict__ gcount, int* __restrict__ deg,
    int* __restrict__ off, int* __restrict__ sortedSrc) {
  __shared__ int ldeg[128];
  __shared__ int loff[128];
  __shared__ int lcur[128];
  const int t = threadIdx.x;
  const int bkt = blockIdx.x;
  const int nbase = bkt << 7;
  const int ebase = gbase[bkt];
  const int cnt = gcount[bkt];
  const int outbase = ebase + PADCAP * bkt;
  if (t < 128) ldeg[t] = 0;
  __syncthreads();
  for (int e = t; e < cnt; e += 256) {
    const int pv = pe[ebase + e];
    atomicAdd(&ldeg[(pv >> 17) & 127], 1);
  }
  __syncthreads();
  if (t < 128) loff[t] = (ldeg[t] + 3) & ~3;  // padded degree
  __syncthreads();
  for (int o = 1; o < 128; o <<= 1) {
    int v = 0;
    if (t >= o && t < 128) v = loff[t - o];
    __syncthreads();
    if (t < 128) loff[t] += v;
    __syncthreads();
  }
  if (t < 128) {
    const int pdeg = (ldeg[t] + 3) & ~3;
    const int ex = loff[t] - pdeg;
    lcur[t] = ex;
    const int n = nbase + t;
    if (n < N_NODES) {
      deg[n] = ldeg[t];
      off[n] = outbase + ex;
    }
  }
  __syncthreads();
  for (int e = t; e < cnt; e += 256) {
    const int pv = pe[ebase + e];
    const int ld = (pv >> 17) & 127;
    const int p = atomicAdd(&lcur[ld], 1);
    sortedSrc[outbase + p] = pv & 0x1FFFF;
  }
  __syncthreads();
  if (t < 128) {
    const int pdeg = (ldeg[t] + 3) & ~3;
    const int ex = loff[t] - pdeg;
    for (int q = ldeg[t]; q < pdeg; ++q)
      sortedSrc[outbase + ex + q] = N_NODES;  // zero row
  }
}

// ------- Layer 1 fp16 MFMA GEMM: [p1 | s1b] = h1 @ [Wneigh1 | Wself1] (+b1) -
__global__ __launch_bounds__(256) void gemm1(
    const float* __restrict__ h1, const _Float16* __restrict__ B1f,
    const float* __restrict__ b1,
    unsigned short* __restrict__ p1u, float* __restrict__ s1b) {
  __shared__ _Float16 lb[64 * 64];  // 8 KB
  const int tid = threadIdx.x;
  {
    const uint4* gb = (const uint4*)B1f;
    for (int i = tid; i < 512; i += 256) {
      const int o = i << 4;
      const int sw = o ^ (((o >> 7) & 7) << 4);
      *(uint4*)((char*)lb + sw) = gb[i];
    }
  }
  __syncthreads();
  const int lane = tid & 63;
  const int wave = tid >> 6;
  const int rowbase = blockIdx.x * 64 + wave * 16;
  const int arow = rowbase + (lane & 15);
  const int rclamp = (arow < N_NODES) ? arow : 0;
  const int ko = (lane >> 4) << 3;

  f32x4 acc[4];
#pragma unroll
  for (int ct = 0; ct < 4; ++ct) acc[ct] = (f32x4){0.f, 0.f, 0.f, 0.f};

  for (int ks = 0; ks < 2; ++ks) {
    float av[8];
    const float* ax = h1 + (size_t)rclamp * HID + ks * 32 + ko;
    *(float4*)&av[0] = *(const float4*)ax;
    *(float4*)&av[4] = *(const float4*)(ax + 4);
    half8 ah;
#pragma unroll
    for (int j = 0; j < 8; ++j) ah[j] = (_Float16)av[j];
    const int kb = ks * 64 + (ko << 1);
#pragma unroll
    for (int ct = 0; ct < 4; ++ct) {
      const int n = ct * 16 + (lane & 15);
      const int boff = (n << 7) + kb;
      const int sb = boff ^ (((boff >> 7) & 7) << 4);
      const half8 bv = *(const half8*)((const char*)lb + sb);
      acc[ct] = __builtin_amdgcn_mfma_f32_16x16x32_f16(ah, bv, acc[ct], 0, 0, 0);
    }
  }
  const int rb4 = rowbase + ((lane >> 4) << 2);
  const int cc = lane & 15;
#pragma unroll
  for (int ct = 0; ct < 2; ++ct) {  // -> p1 (bf16)
#pragma unroll
    for (int j = 0; j < 4; ++j) {
      const int r = rb4 + j;
      if (r < N_NODES) p1u[(size_t)r * OUT_DIM + ct * 16 + cc] = bf16rne(acc[ct][j]);
    }
  }
#pragma unroll
  for (int ct = 2; ct < 4; ++ct) {  // -> s1b (fp32 + bias)
    const float bias = b1[(ct - 2) * 16 + cc];
#pragma unroll
    for (int j = 0; j < 4; ++j) {
      const int r = rb4 + j;
      if (r < N_NODES)
        s1b[(size_t)r * OUT_DIM + (ct - 2) * 16 + cc] = acc[ct][j] + bias;
    }
  }
}

// ------- Fused layer-0 aggregate + mean + LN + ReLU -> h1 (2 nodes/wave) ----
// Maskless: edge lists padded to x4 with zero-row (index N_NODES).
__global__ __launch_bounds__(256) void aggc0(
    const int* __restrict__ sortedSrc, const int* __restrict__ off,
    const int* __restrict__ deg, const unsigned short* __restrict__ p0u,
    const float* __restrict__ s0b, const float* __restrict__ g,
    const float* __restrict__ be, float* __restrict__ h1) {
  const int lane = threadIdx.x & 63;
  const int h = lane >> 5;          // node half
  const int grp = (lane >> 3) & 3;  // 4 edge groups
  const int sl = lane & 7;          // 8 feature slices
  const int i = blockIdx.x * 8 + ((threadIdx.x >> 6) << 1) + h;
  const int st = off[i];
  const int dg = deg[i];
  const int dgp = (dg + 3) & ~3;
  const int dgmaxp = max(dgp, __shfl_xor(dgp, 32));
  float acc[8];
#pragma unroll
  for (int f = 0; f < 8; ++f) acc[f] = 0.f;

  for (int base = 0; base < dgmaxp; base += 32) {
    const int cntp = dgp - base;
    const int l5 = lane & 31;
    const int idx = (l5 < cntp) ? sortedSrc[st + base + l5] : N_NODES;
    const int cm = min(32, dgmaxp - base);  // multiple of 4
    for (int j = 0; j * 4 < cm; ++j) {
      const int e = j * 4 + grp;
      const int srcn = __shfl(idx, (h << 5) | e);
      const uint4 q = *(const uint4*)(p0u + (size_t)srcn * HID + sl * 8);
      acc[0] += uflo(q.x); acc[1] += ufhi(q.x);
      acc[2] += uflo(q.y); acc[3] += ufhi(q.y);
      acc[4] += uflo(q.z); acc[5] += ufhi(q.z);
      acc[6] += uflo(q.w); acc[7] += ufhi(q.w);
    }
  }
  // fold edge groups (xor over lane bits 3,4 — stays within node half)
#pragma unroll
  for (int mk = 8; mk < 32; mk <<= 1) {
#pragma unroll
    for (int f = 0; f < 8; ++f) acc[f] += __shfl_xor(acc[f], mk);
  }
  const float inv = 1.0f / fmaxf((float)dg, 1.0f);
  float z[8];
  const float4 sb0 = *(const float4*)(s0b + (size_t)i * HID + sl * 8);
  const float4 sb1 = *(const float4*)(s0b + (size_t)i * HID + sl * 8 + 4);
  z[0] = sb0.x + acc[0] * inv; z[1] = sb0.y + acc[1] * inv;
  z[2] = sb0.z + acc[2] * inv; z[3] = sb0.w + acc[3] * inv;
  z[4] = sb1.x + acc[4] * inv; z[5] = sb1.y + acc[5] * inv;
  z[6] = sb1.z + acc[6] * inv; z[7] = sb1.w + acc[7] * inv;
  float pm = 0.f;
#pragma unroll
  for (int f = 0; f < 8; ++f) pm += z[f];
#pragma unroll
  for (int mk = 1; mk < 8; mk <<= 1) pm += __shfl_xor(pm, mk);
  const float mean = pm * (1.0f / 64.0f);
  float pv = 0.f;
#pragma unroll
  for (int f = 0; f < 8; ++f) {
    z[f] -= mean;
    pv += z[f] * z[f];
  }
#pragma unroll
  for (int mk = 1; mk < 8; mk <<= 1) pv += __shfl_xor(pv, mk);
  const float rstd = rsqrtf(pv * (1.0f / 64.0f) + LN_EPS);
  if (grp == 0) {
    const float4 gv0 = *(const float4*)(g + sl * 8);
    const float4 gv1 = *(const float4*)(g + sl * 8 + 4);
    const float4 bv0 = *(const float4*)(be + sl * 8);
    const float4 bv1 = *(const float4*)(be + sl * 8 + 4);
    float4 o0, o1;
    o0.x = fmaxf(z[0] * rstd * gv0.x + bv0.x, 0.f);
    o0.y = fmaxf(z[1] * rstd * gv0.y + bv0.y, 0.f);
    o0.z = fmaxf(z[2] * rstd * gv0.z + bv0.z, 0.f);
    o0.w = fmaxf(z[3] * rstd * gv0.w + bv0.w, 0.f);
    o1.x = fmaxf(z[4] * rstd * gv1.x + bv1.x, 0.f);
    o1.y = fmaxf(z[5] * rstd * gv1.y + bv1.y, 0.f);
    o1.z = fmaxf(z[6] * rstd * gv1.z + bv1.z, 0.f);
    o1.w = fmaxf(z[7] * rstd * gv1.w + bv1.w, 0.f);
    *(float4*)(h1 + (size_t)i * HID + sl * 8) = o0;
    *(float4*)(h1 + (size_t)i * HID + sl * 8 + 4) = o1;
  }
}

// ------- Fused layer-1 aggregate + mean + LN + ReLU -> out (4 nodes/wave) ---
__global__ __launch_bounds__(256) void aggc1(
    const int* __restrict__ sortedSrc, const int* __restrict__ off,
    const int* __restrict__ deg, const unsigned short* __restrict__ p1u,
    const float* __restrict__ s1b, const float* __restrict__ g,
    const float* __restrict__ be, float* __restrict__ out) {
  const int lane = threadIdx.x & 63;
  const int q4 = lane >> 4;         // node quarter
  const int grp = (lane >> 2) & 3;  // 4 edge groups
  const int sl = lane & 3;          // 4 feature slices
  const int i = blockIdx.x * 16 + ((threadIdx.x >> 6) << 2) + q4;
  const int st = off[i];
  const int dg = deg[i];
  const int dgp = (dg + 3) & ~3;
  int dm = max(dgp, __shfl_xor(dgp, 16));
  const int dgmaxp = max(dm, __shfl_xor(dm, 32));
  float acc[8];
#pragma unroll
  for (int f = 0; f < 8; ++f) acc[f] = 0.f;

  for (int base = 0; base < dgmaxp; base += 16) {
    const int cntp = dgp - base;
    const int l4 = lane & 15;
    const int idx = (l4 < cntp) ? sortedSrc[st + base + l4] : N_NODES;
    const int cm = min(16, dgmaxp - base);  // multiple of 4
    for (int j = 0; j * 4 < cm; ++j) {
      const int e = j * 4 + grp;
      const int srcn = __shfl(idx, (q4 << 4) | e);
      const uint4 qv = *(const uint4*)(p1u + (size_t)srcn * OUT_DIM + sl * 8);
      acc[0] += uflo(qv.x); acc[1] += ufhi(qv.x);
      acc[2] += uflo(qv.y); acc[3] += ufhi(qv.y);
      acc[4] += uflo(qv.z); acc[5] += ufhi(qv.z);
      acc[6] += uflo(qv.w); acc[7] += ufhi(qv.w);
    }
  }
  // fold edge groups (xor over lane bits 2,3 — stays within node quarter)
#pragma unroll
  for (int mk = 4; mk < 16; mk <<= 1) {
#pragma unroll
    for (int f = 0; f < 8; ++f) acc[f] += __shfl_xor(acc[f], mk);
  }
  const float inv = 1.0f / fmaxf((float)dg, 1.0f);
  float z[8];
  const float4 sb0 = *(const float4*)(s1b + (size_t)i * OUT_DIM + sl * 8);
  const float4 sb1 = *(const float4*)(s1b + (size_t)i * OUT_DIM + sl * 8 + 4);
  z[0] = sb0.x + acc[0] * inv; z[1] = sb0.y + acc[1] * inv;
  z[2] = sb0.z + acc[2] * inv; z[3] = sb0.w + acc[3] * inv;
  z[4] = sb1.x + acc[4] * inv; z[5] = sb1.y + acc[5] * inv;
  z[6] = sb1.z + acc[6] * inv; z[7] = sb1.w + acc[7] * inv;
  float pm = 0.f;
#pragma unroll
  for (int f = 0; f < 8; ++f) pm += z[f];
#pragma unroll
  for (int mk = 1; mk < 4; mk <<= 1) pm += __shfl_xor(pm, mk);
  const float mean = pm * (1.0f / 32.0f);
  float pv = 0.f;
#pragma unroll
  for (int f = 0; f < 8; ++f) {
    z[f] -= mean;
    pv += z[f] * z[f];
  }
#pragma unroll
  for (int mk = 1; mk < 4; mk <<= 1) pv += __shfl_xor(pv, mk);
  const float rstd = rsqrtf(pv * (1.0f / 32.0f) + LN_EPS);
  if (grp == 0) {
    const float4 gv0 = *(const float4*)(g + sl * 8);
    const float4 gv1 = *(const float4*)(g + sl * 8 + 4);
    const float4 bv0 = *(const float4*)(be + sl * 8);
    const float4 bv1 = *(const float4*)(be + sl * 8 + 4);
    float4 o0, o1;
    o0.x = fmaxf(z[0] * rstd * gv0.x + bv0.x, 0.f);
    o0.y = fmaxf(z[1] * rstd * gv0.y + bv0.y, 0.f);
    o0.z = fmaxf(z[2] * rstd * gv0.z + bv0.z, 0.f);
    o0.w = fmaxf(z[3] * rstd * gv0.w + bv0.w, 0.f);
    o1.x = fmaxf(z[4] * rstd * gv1.x + bv1.x, 0.f);
    o1.y = fmaxf(z[5] * rstd * gv1.y + bv1.y, 0.f);
    o1.z = fmaxf(z[6] * rstd * gv1.z + bv1.z, 0.f);
    o1.w = fmaxf(z[7] * rstd * gv1.w + bv1.w, 0.f);
    *(float4*)(out + (size_t)i * OUT_DIM + sl * 8) = o0;
    *(float4*)(out + (size_t)i * OUT_DIM + sl * 8 + 4) = o1;
  }
}

extern "C" void kernel_launch(void* const* d_in, const int* in_sizes, int n_in,
                              void* d_out, int out_size, void* d_ws, size_t ws_size,
                              hipStream_t stream) {
  const float* x       = (const float*)d_in[0];
  const int*   edges   = (const int*)d_in[1];
  const float* Wself0  = (const float*)d_in[2];
  const float* Wneigh0 = (const float*)d_in[3];
  const float* b0      = (const float*)d_in[4];
  const float* g0      = (const float*)d_in[5];
  const float* be0     = (const float*)d_in[6];
  const float* Wself1  = (const float*)d_in[7];
  const float* Wneigh1 = (const float*)d_in[8];
  const float* b1      = (const float*)d_in[9];
  const float* g1      = (const float*)d_in[10];
  const float* be1     = (const float*)d_in[11];

  // ---- 256-byte-aligned workspace carve-out (fixes R10's p0u/p1u/s0b
  //      row-straddle: misaligned 128B/64B rows doubled HBM fetch) ----
  char* base = (char*)d_ws;
  size_t o = 0;
  auto carve = [&](size_t bytes) {
    char* p = base + o;
    o += (bytes + 255) & ~(size_t)255;
    return p;
  };
  int* flag      = (int*)carve(64 * 4);
  int* gcount    = (int*)carve(1024 * 4);
  int* gbase     = (int*)carve(1024 * 4);
  int* blkbase   = (int*)carve((size_t)NPBLK * NBKT * 4);
  int* deg       = (int*)carve((size_t)N_NODES * 4);
  int* off       = (int*)carve((size_t)N_NODES * 4);
  int* sortedSrc = (int*)carve(1950000 * 4);  // 1.6M + PADCAP*NBKT
  int* pe        = (int*)carve(6500000);      // 1.62M ints; later p1u overlay
  _Float16* B0f  = (_Float16*)carve(128 * 128 * 2);
  _Float16* B1f  = (_Float16*)carve(64 * 64 * 2);
  unsigned short* p0u = (unsigned short*)carve(((size_t)N_NODES + 2) * HID * 2);
  float* s0b = (float*)carve((size_t)N_NODES * HID * 4);
  float* h1  = (float*)carve((size_t)N_NODES * HID * 4);
  unsigned short* p1u = (unsigned short*)pe;  // overlay (pe dead after csr)
  float* s1b = s0b;                           // overlay (s0b dead after aggc0)

  hipMemsetAsync(gcount, 0, NBKT * sizeof(int), stream);
  hipMemsetAsync(p0u + (size_t)N_NODES * HID, 0, HID * sizeof(unsigned short),
                 stream);  // zero row for aggc0

  detect_edges<<<1, 256, 0, stream>>>(edges, flag);
  convW<<<80, 256, 0, stream>>>(Wneigh0, Wself0, Wneigh1, Wself1, B0f, B1f);
  g0pc<<<NPBLK + 2 * G0T, 256, 0, stream>>>(x, B0f, b0, p0u, s0b,
                                            edges, flag, gcount, blkbase);
  part_scan<<<1, 256, 0, stream>>>(gcount, gbase);
  part_scatter<<<NPBLK, 256, 0, stream>>>(edges, flag, gbase, blkbase, pe);
  bucket_csr<<<NBKT, 256, 0, stream>>>(pe, gbase, gcount, deg, off, sortedSrc);

  // pe is dead now; zero p1u's zero-row before aggc1
  hipMemsetAsync(p1u + (size_t)N_NODES * OUT_DIM, 0,
                 OUT_DIM * sizeof(unsigned short), stream);

  aggc0<<<N_NODES / 8, 256, 0, stream>>>(sortedSrc, off, deg, p0u, s0b,
                                         g0, be0, h1);
  gemm1<<<(N_NODES + 63) / 64, 256, 0, stream>>>(h1, B1f, b1, p1u, s1b);
  aggc1<<<N_NODES / 16, 256, 0, stream>>>(sortedSrc, off, deg, p1u, s1b,
                                          g1, be1, (float*)d_out);
}

// Round 12
// 162.360 us; speedup vs baseline: 1.1219x; 1.0232x over previous
//
#include <hip/hip_runtime.h>
#include <hip/hip_bf16.h>

#define N_NODES 100000
#define N_EDGES 1600000
#define IN_DIM 128
#define HID 64
#define OUT_DIM 32
#define LN_EPS 1e-5f
#define NBKT 782            // ceil(100000/128) coarse buckets (128 nodes each)
#define NPBLK 500           // partition blocks
#define PAIRS_PER_BLK 1600  // 500*1600*2 = 1.6M edges
#define G0T 1563            // gemm0 row-tiles: ceil(100000/64)
#define PADCAP 384          // max padding per bucket (128 nodes * 3)

typedef __attribute__((ext_vector_type(8))) _Float16 half8;
typedef __attribute__((ext_vector_type(8))) short short8;
typedef __attribute__((ext_vector_type(4))) float f32x4;

__device__ __forceinline__ float uflo(unsigned int u) {
  return __uint_as_float(u << 16);
}
__device__ __forceinline__ float ufhi(unsigned int u) {
  return __uint_as_float(u & 0xffff0000u);
}
__device__ __forceinline__ unsigned short bf16rne(float f) {
  unsigned int u = __float_as_uint(f);
  unsigned int r = u + 0x7fffu + ((u >> 16) & 1u);
  return (unsigned short)(r >> 16);
}
__device__ __forceinline__ unsigned int pk(float lo, float hi) {
  return (unsigned int)bf16rne(lo) | ((unsigned int)bf16rne(hi) << 16);
}

// ---------- Edge dtype detect: int64 (high words all 0) vs int32 ------------
__global__ void detect_edges(const int* __restrict__ w, int* __restrict__ flag) {
  __shared__ int any;
  if (threadIdx.x == 0) any = 0;
  __syncthreads();
  if (w[2 * threadIdx.x + 1] != 0) any = 1;
  __syncthreads();
  if (threadIdx.x == 0) flag[0] = any ? 0 : 1;  // 1 => int64 layout
}

// ---------- Weight convert: B0 fp16 [128n][128k], B1 bf16 [64n][64k] --------
__global__ __launch_bounds__(256) void convW(
    const float* __restrict__ Wn0, const float* __restrict__ Ws0,
    const float* __restrict__ Wn1, const float* __restrict__ Ws1,
    _Float16* __restrict__ B0f, unsigned short* __restrict__ B1u) {
  const int i = blockIdx.x * 256 + threadIdx.x;
  if (i < 128 * 128) {
    const int n = i >> 7, k = i & 127;
    const float w = (n < 64) ? Wn0[k * 64 + n] : Ws0[k * 64 + (n - 64)];
    B0f[i] = (_Float16)w;
  } else if (i < 128 * 128 + 64 * 64) {
    const int j = i - 128 * 128;
    const int n = j >> 6, k = j & 63;
    const float w = (n < 32) ? Wn1[k * 32 + n] : Ws1[k * 32 + (n - 32)];
    B1u[j] = bf16rne(w);
  }
}

// ---------- FUSED: part_count (blocks 0..499) || gemm0 (blocks 500..3625) ---
// gemm0: A prefetched up-front (8 independent 16B loads issued BEFORE the
// LDS staging loads, so one vmcnt drain covers both — R11 was 4 dependent
// HBM round-trips per wave). colgrp 0 -> p0u (bf16), colgrp 1 -> s0bu (bf16).
__global__ __launch_bounds__(256) void g0pc(
    const float* __restrict__ x, const _Float16* __restrict__ B0f,
    const float* __restrict__ b0,
    unsigned short* __restrict__ p0u, unsigned short* __restrict__ s0bu,
    const int* __restrict__ w, const int* __restrict__ flag,
    int* __restrict__ gcount, int* __restrict__ blkbase) {
  __shared__ _Float16 lb[64 * 128];  // 16 KB (pc path: int hist scratch)
  const int tid = threadIdx.x;

  if (blockIdx.x < NPBLK) {
    // ---------------- part_count path ----------------
    int* h = (int*)lb;
    const int b = blockIdx.x;
    for (int i = tid; i < NBKT; i += 256) h[i] = 0;
    __syncthreads();
    const int i64 = flag[0];
    const int pEnd = (b + 1) * PAIRS_PER_BLK;
    for (int p = b * PAIRS_PER_BLK + tid; p < pEnd; p += 256) {
      int d0, d1;
      if (i64) {
        const int4 vd = *(const int4*)(w + 2 * (size_t)N_EDGES + 4 * (size_t)p);
        d0 = vd.x; d1 = vd.z;
      } else {
        const int2 vd = *(const int2*)(w + (size_t)N_EDGES + 2 * (size_t)p);
        d0 = vd.x; d1 = vd.y;
      }
      atomicAdd(&h[d0 >> 7], 1);
      atomicAdd(&h[d1 >> 7], 1);
    }
    __syncthreads();
    for (int i = tid; i < NBKT; i += 256)
      blkbase[b * NBKT + i] = atomicAdd(&gcount[i], h[i]);  // coalesced
    return;
  }

  // ---------------- gemm0 path (64 rows x 64 cols per block) ----------------
  const int gb = blockIdx.x - NPBLK;
  const int colgrp = (gb >= G0T) ? 1 : 0;
  const int rowblk = colgrp ? (gb - G0T) : gb;
  const int lane = tid & 63;
  const int wave = tid >> 6;
  const int rowbase = rowblk * 64 + wave * 16;
  const int arow = rowbase + (lane & 15);
  const int rclamp = (arow < N_NODES) ? arow : 0;
  const int ko = (lane >> 4) << 3;  // 0,8,16,24

  // Prefetch all A (4 k-steps x 32B), independent loads, before staging.
  float av[32];
  {
    const float* ax = x + (size_t)rclamp * IN_DIM + ko;
#pragma unroll
    for (int ks = 0; ks < 4; ++ks) {
      *(float4*)&av[ks * 8] = *(const float4*)(ax + ks * 32);
      *(float4*)&av[ks * 8 + 4] = *(const float4*)(ax + ks * 32 + 4);
    }
  }
  {
    const uint4* gsrc = (const uint4*)(B0f + (colgrp << 13));  // 64*128 halfs
    for (int i = tid; i < 1024; i += 256) {
      const int o = i << 4;
      const int sw = o ^ (((o >> 8) & 7) << 4);
      *(uint4*)((char*)lb + sw) = gsrc[i];
    }
  }
  __syncthreads();

  half8 ah[4];
#pragma unroll
  for (int ks = 0; ks < 4; ++ks) {
#pragma unroll
    for (int j = 0; j < 8; ++j) ah[ks][j] = (_Float16)av[ks * 8 + j];
  }

  f32x4 acc[4];
#pragma unroll
  for (int ct = 0; ct < 4; ++ct) acc[ct] = (f32x4){0.f, 0.f, 0.f, 0.f};

#pragma unroll
  for (int ks = 0; ks < 4; ++ks) {
    const int kb = ks * 64 + (ko << 1);
#pragma unroll
    for (int ct = 0; ct < 4; ++ct) {
      const int n = ct * 16 + (lane & 15);
      const int boff = (n << 8) + kb;
      const int sb = boff ^ (((boff >> 8) & 7) << 4);
      const half8 bv = *(const half8*)((const char*)lb + sb);
      acc[ct] = __builtin_amdgcn_mfma_f32_16x16x32_f16(ah[ks], bv, acc[ct], 0, 0, 0);
    }
  }
  const int rb4 = rowbase + ((lane >> 4) << 2);
  const int cc = lane & 15;
  if (colgrp == 0) {  // -> p0u (bf16)
#pragma unroll
    for (int ct = 0; ct < 4; ++ct) {
#pragma unroll
      for (int j = 0; j < 4; ++j) {
        const int r = rb4 + j;
        if (r < N_NODES) p0u[(size_t)r * HID + ct * 16 + cc] = bf16rne(acc[ct][j]);
      }
    }
  } else {  // -> s0bu (bf16 + bias)
#pragma unroll
    for (int ct = 0; ct < 4; ++ct) {
      const float bias = b0[ct * 16 + cc];
#pragma unroll
      for (int j = 0; j < 4; ++j) {
        const int r = rb4 + j;
        if (r < N_NODES)
          s0bu[(size_t)r * HID + ct * 16 + cc] = bf16rne(acc[ct][j] + bias);
      }
    }
  }
}

// ---------- Phase B: single-block exclusive scan of 782 bucket counts -------
__global__ __launch_bounds__(256) void part_scan(
    const int* __restrict__ gcount, int* __restrict__ gbase) {
  __shared__ int lds[256];
  const int t = threadIdx.x;
  int v[4];
  int s = 0;
#pragma unroll
  for (int j = 0; j < 4; ++j) {
    const int idx = t * 4 + j;
    v[j] = (idx < NBKT) ? gcount[idx] : 0;
    s += v[j];
  }
  lds[t] = s;
  __syncthreads();
  for (int o = 1; o < 256; o <<= 1) {
    const int val = (t >= o) ? lds[t - o] : 0;
    __syncthreads();
    lds[t] += val;
    __syncthreads();
  }
  int run = lds[t] - s;
#pragma unroll
  for (int j = 0; j < 4; ++j) {
    const int idx = t * 4 + j;
    if (idx < NBKT) gbase[idx] = run;
    run += v[j];
  }
}

// ---------- Phase C: scatter packed edges into coarse-bucket regions --------
// pe[e] = src | (localdst << 17)   (src < 2^17, localdst < 128)
__global__ __launch_bounds__(256) void part_scatter(
    const int* __restrict__ w, const int* __restrict__ flag,
    const int* __restrict__ gbase, const int* __restrict__ blkbase,
    int* __restrict__ pe) {
  __shared__ int cur[NBKT];
  const int t = threadIdx.x, b = blockIdx.x;
  for (int i = t; i < NBKT; i += 256)
    cur[i] = gbase[i] + blkbase[b * NBKT + i];
  __syncthreads();
  const int i64 = flag[0];
  const int pEnd = (b + 1) * PAIRS_PER_BLK;
  for (int p = b * PAIRS_PER_BLK + t; p < pEnd; p += 256) {
    int s0, s1, d0, d1;
    if (i64) {
      const int4 vs = *(const int4*)(w + 4 * (size_t)p);
      const int4 vd = *(const int4*)(w + 2 * (size_t)N_EDGES + 4 * (size_t)p);
      s0 = vs.x; s1 = vs.z;
      d0 = vd.x; d1 = vd.z;
    } else {
      const int2 vs = *(const int2*)(w + 2 * (size_t)p);
      const int2 vd = *(const int2*)(w + (size_t)N_EDGES + 2 * (size_t)p);
      s0 = vs.x; s1 = vs.y;
      d0 = vd.x; d1 = vd.y;
    }
    const int sl0 = atomicAdd(&cur[d0 >> 7], 1);
    pe[sl0] = s0 | ((d0 & 127) << 17);
    const int sl1 = atomicAdd(&cur[d1 >> 7], 1);
    pe[sl1] = s1 | ((d1 & 127) << 17);
  }
}

// ---------- Phase D: per-bucket CSR build, padded to x4 with zero-row -------
__global__ __launch_bounds__(256) void bucket_csr(
    const int* __restrict__ pe, const int* __restrict__ gbase,
    const int* __restrict__ gcount, int* __restrict__ deg,
    int* __restrict__ off, int* __restrict__ sortedSrc) {
  __shared__ int ldeg[128];
  __shared__ int loff[128];
  __shared__ int lcur[128];
  const int t = threadIdx.x;
  const int bkt = blockIdx.x;
  const int nbase = bkt << 7;
  const int ebase = gbase[bkt];
  const int cnt = gcount[bkt];
  const int outbase = ebase + PADCAP * bkt;
  if (t < 128) ldeg[t] = 0;
  __syncthreads();
  for (int e = t; e < cnt; e += 256) {
    const int pv = pe[ebase + e];
    atomicAdd(&ldeg[(pv >> 17) & 127], 1);
  }
  __syncthreads();
  if (t < 128) loff[t] = (ldeg[t] + 3) & ~3;  // padded degree
  __syncthreads();
  for (int o = 1; o < 128; o <<= 1) {
    int v = 0;
    if (t >= o && t < 128) v = loff[t - o];
    __syncthreads();
    if (t < 128) loff[t] += v;
    __syncthreads();
  }
  if (t < 128) {
    const int pdeg = (ldeg[t] + 3) & ~3;
    const int ex = loff[t] - pdeg;
    lcur[t] = ex;
    const int n = nbase + t;
    if (n < N_NODES) {
      deg[n] = ldeg[t];
      off[n] = outbase + ex;
    }
  }
  __syncthreads();
  for (int e = t; e < cnt; e += 256) {
    const int pv = pe[ebase + e];
    const int ld = (pv >> 17) & 127;
    const int p = atomicAdd(&lcur[ld], 1);
    sortedSrc[outbase + p] = pv & 0x1FFFF;
  }
  __syncthreads();
  if (t < 128) {
    const int pdeg = (ldeg[t] + 3) & ~3;
    const int ex = loff[t] - pdeg;
    for (int q = ldeg[t]; q < pdeg; ++q)
      sortedSrc[outbase + ex + q] = N_NODES;  // zero row
  }
}

// ------- Layer 1 bf16 MFMA GEMM: [p1 | s1b] = h1 @ [Wn1 | Ws1] (+b1) --------
// A loaded DIRECTLY as bf16 from h1u (no conversion); prefetched up-front.
__global__ __launch_bounds__(256) void gemm1(
    const unsigned short* __restrict__ h1u, const unsigned short* __restrict__ B1u,
    const float* __restrict__ b1,
    unsigned short* __restrict__ p1u, unsigned short* __restrict__ s1bu) {
  __shared__ unsigned short lb[64 * 64];  // 8 KB
  const int tid = threadIdx.x;
  const int lane = tid & 63;
  const int wave = tid >> 6;
  const int rowbase = blockIdx.x * 64 + wave * 16;
  const int arow = rowbase + (lane & 15);
  const int rclamp = (arow < N_NODES) ? arow : 0;
  const int ko = (lane >> 4) << 3;

  short8 ah[2];
  {
    const unsigned short* ax = h1u + (size_t)rclamp * HID + ko;
    ah[0] = *(const short8*)ax;
    ah[1] = *(const short8*)(ax + 32);
  }
  {
    const uint4* gb = (const uint4*)B1u;
    for (int i = tid; i < 512; i += 256) {
      const int o = i << 4;
      const int sw = o ^ (((o >> 7) & 7) << 4);
      *(uint4*)((char*)lb + sw) = gb[i];
    }
  }
  __syncthreads();

  f32x4 acc[4];
#pragma unroll
  for (int ct = 0; ct < 4; ++ct) acc[ct] = (f32x4){0.f, 0.f, 0.f, 0.f};

#pragma unroll
  for (int ks = 0; ks < 2; ++ks) {
    const int kb = ks * 64 + (ko << 1);
#pragma unroll
    for (int ct = 0; ct < 4; ++ct) {
      const int n = ct * 16 + (lane & 15);
      const int boff = (n << 7) + kb;
      const int sb = boff ^ (((boff >> 7) & 7) << 4);
      const short8 bv = *(const short8*)((const char*)lb + sb);
      acc[ct] = __builtin_amdgcn_mfma_f32_16x16x32_bf16(ah[ks], bv, acc[ct], 0, 0, 0);
    }
  }
  const int rb4 = rowbase + ((lane >> 4) << 2);
  const int cc = lane & 15;
#pragma unroll
  for (int ct = 0; ct < 2; ++ct) {  // -> p1 (bf16)
#pragma unroll
    for (int j = 0; j < 4; ++j) {
      const int r = rb4 + j;
      if (r < N_NODES) p1u[(size_t)r * OUT_DIM + ct * 16 + cc] = bf16rne(acc[ct][j]);
    }
  }
#pragma unroll
  for (int ct = 2; ct < 4; ++ct) {  // -> s1bu (bf16 + bias)
#pragma unroll
    for (int j = 0; j < 4; ++j) {
      const int r = rb4 + j;
      if (r < N_NODES)
        s1bu[(size_t)r * OUT_DIM + (ct - 2) * 16 + cc] =
            bf16rne(acc[ct][j] + b1[(ct - 2) * 16 + cc]);
    }
  }
}

// ------- Fused layer-0 aggregate + mean + LN + ReLU -> h1u (2 nodes/wave) ---
__global__ __launch_bounds__(256) void aggc0(
    const int* __restrict__ sortedSrc, const int* __restrict__ off,
    const int* __restrict__ deg, const unsigned short* __restrict__ p0u,
    const unsigned short* __restrict__ s0bu, const float* __restrict__ g,
    const float* __restrict__ be, unsigned short* __restrict__ h1u) {
  const int lane = threadIdx.x & 63;
  const int h = lane >> 5;          // node half
  const int grp = (lane >> 3) & 3;  // 4 edge groups
  const int sl = lane & 7;          // 8 feature slices
  const int i = blockIdx.x * 8 + ((threadIdx.x >> 6) << 1) + h;
  const int st = off[i];
  const int dg = deg[i];
  const int dgp = (dg + 3) & ~3;
  const int dgmaxp = max(dgp, __shfl_xor(dgp, 32));
  float acc[8];
#pragma unroll
  for (int f = 0; f < 8; ++f) acc[f] = 0.f;

  for (int base = 0; base < dgmaxp; base += 32) {
    const int cntp = dgp - base;
    const int l5 = lane & 31;
    const int idx = (l5 < cntp) ? sortedSrc[st + base + l5] : N_NODES;
    const int cm = min(32, dgmaxp - base);  // multiple of 4
    for (int j = 0; j * 4 < cm; ++j) {
      const int e = j * 4 + grp;
      const int srcn = __shfl(idx, (h << 5) | e);
      const uint4 q = *(const uint4*)(p0u + (size_t)srcn * HID + sl * 8);
      acc[0] += uflo(q.x); acc[1] += ufhi(q.x);
      acc[2] += uflo(q.y); acc[3] += ufhi(q.y);
      acc[4] += uflo(q.z); acc[5] += ufhi(q.z);
      acc[6] += uflo(q.w); acc[7] += ufhi(q.w);
    }
  }
  // fold edge groups (xor over lane bits 3,4 — stays within node half)
#pragma unroll
  for (int mk = 8; mk < 32; mk <<= 1) {
#pragma unroll
    for (int f = 0; f < 8; ++f) acc[f] += __shfl_xor(acc[f], mk);
  }
  const float inv = 1.0f / fmaxf((float)dg, 1.0f);
  float z[8];
  const uint4 sbv = *(const uint4*)(s0bu + (size_t)i * HID + sl * 8);
  z[0] = uflo(sbv.x) + acc[0] * inv; z[1] = ufhi(sbv.x) + acc[1] * inv;
  z[2] = uflo(sbv.y) + acc[2] * inv; z[3] = ufhi(sbv.y) + acc[3] * inv;
  z[4] = uflo(sbv.z) + acc[4] * inv; z[5] = ufhi(sbv.z) + acc[5] * inv;
  z[6] = uflo(sbv.w) + acc[6] * inv; z[7] = ufhi(sbv.w) + acc[7] * inv;
  float pm = 0.f;
#pragma unroll
  for (int f = 0; f < 8; ++f) pm += z[f];
#pragma unroll
  for (int mk = 1; mk < 8; mk <<= 1) pm += __shfl_xor(pm, mk);
  const float mean = pm * (1.0f / 64.0f);
  float pv = 0.f;
#pragma unroll
  for (int f = 0; f < 8; ++f) {
    z[f] -= mean;
    pv += z[f] * z[f];
  }
#pragma unroll
  for (int mk = 1; mk < 8; mk <<= 1) pv += __shfl_xor(pv, mk);
  const float rstd = rsqrtf(pv * (1.0f / 64.0f) + LN_EPS);
  if (grp == 0) {
    const float4 gv0 = *(const float4*)(g + sl * 8);
    const float4 gv1 = *(const float4*)(g + sl * 8 + 4);
    const float4 bv0 = *(const float4*)(be + sl * 8);
    const float4 bv1 = *(const float4*)(be + sl * 8 + 4);
    uint4 ov;
    ov.x = pk(fmaxf(z[0] * rstd * gv0.x + bv0.x, 0.f),
              fmaxf(z[1] * rstd * gv0.y + bv0.y, 0.f));
    ov.y = pk(fmaxf(z[2] * rstd * gv0.z + bv0.z, 0.f),
              fmaxf(z[3] * rstd * gv0.w + bv0.w, 0.f));
    ov.z = pk(fmaxf(z[4] * rstd * gv1.x + bv1.x, 0.f),
              fmaxf(z[5] * rstd * gv1.y + bv1.y, 0.f));
    ov.w = pk(fmaxf(z[6] * rstd * gv1.z + bv1.z, 0.f),
              fmaxf(z[7] * rstd * gv1.w + bv1.w, 0.f));
    *(uint4*)(h1u + (size_t)i * HID + sl * 8) = ov;
  }
}

// ------- Fused layer-1 aggregate + mean + LN + ReLU -> out (4 nodes/wave) ---
__global__ __launch_bounds__(256) void aggc1(
    const int* __restrict__ sortedSrc, const int* __restrict__ off,
    const int* __restrict__ deg, const unsigned short* __restrict__ p1u,
    const unsigned short* __restrict__ s1bu, const float* __restrict__ g,
    const float* __restrict__ be, float* __restrict__ out) {
  const int lane = threadIdx.x & 63;
  const int q4 = lane >> 4;         // node quarter
  const int grp = (lane >> 2) & 3;  // 4 edge groups
  const int sl = lane & 3;          // 4 feature slices
  const int i = blockIdx.x * 16 + ((threadIdx.x >> 6) << 2) + q4;
  const int st = off[i];
  const int dg = deg[i];
  const int dgp = (dg + 3) & ~3;
  int dm = max(dgp, __shfl_xor(dgp, 16));
  const int dgmaxp = max(dm, __shfl_xor(dm, 32));
  float acc[8];
#pragma unroll
  for (int f = 0; f < 8; ++f) acc[f] = 0.f;

  for (int base = 0; base < dgmaxp; base += 16) {
    const int cntp = dgp - base;
    const int l4 = lane & 15;
    const int idx = (l4 < cntp) ? sortedSrc[st + base + l4] : N_NODES;
    const int cm = min(16, dgmaxp - base);  // multiple of 4
    for (int j = 0; j * 4 < cm; ++j) {
      const int e = j * 4 + grp;
      const int srcn = __shfl(idx, (q4 << 4) | e);
      const uint4 qv = *(const uint4*)(p1u + (size_t)srcn * OUT_DIM + sl * 8);
      acc[0] += uflo(qv.x); acc[1] += ufhi(qv.x);
      acc[2] += uflo(qv.y); acc[3] += ufhi(qv.y);
      acc[4] += uflo(qv.z); acc[5] += ufhi(qv.z);
      acc[6] += uflo(qv.w); acc[7] += ufhi(qv.w);
    }
  }
  // fold edge groups (xor over lane bits 2,3 — stays within node quarter)
#pragma unroll
  for (int mk = 4; mk < 16; mk <<= 1) {
#pragma unroll
    for (int f = 0; f < 8; ++f) acc[f] += __shfl_xor(acc[f], mk);
  }
  const float inv = 1.0f / fmaxf((float)dg, 1.0f);
  float z[8];
  const uint4 sbv = *(const uint4*)(s1bu + (size_t)i * OUT_DIM + sl * 8);
  z[0] = uflo(sbv.x) + acc[0] * inv; z[1] = ufhi(sbv.x) + acc[1] * inv;
  z[2] = uflo(sbv.y) + acc[2] * inv; z[3] = ufhi(sbv.y) + acc[3] * inv;
  z[4] = uflo(sbv.z) + acc[4] * inv; z[5] = ufhi(sbv.z) + acc[5] * inv;
  z[6] = uflo(sbv.w) + acc[6] * inv; z[7] = ufhi(sbv.w) + acc[7] * inv;
  float pm = 0.f;
#pragma unroll
  for (int f = 0; f < 8; ++f) pm += z[f];
#pragma unroll
  for (int mk = 1; mk < 4; mk <<= 1) pm += __shfl_xor(pm, mk);
  const float mean = pm * (1.0f / 32.0f);
  float pv = 0.f;
#pragma unroll
  for (int f = 0; f < 8; ++f) {
    z[f] -= mean;
    pv += z[f] * z[f];
  }
#pragma unroll
  for (int mk = 1; mk < 4; mk <<= 1) pv += __shfl_xor(pv, mk);
  const float rstd = rsqrtf(pv * (1.0f / 32.0f) + LN_EPS);
  if (grp == 0) {
    const float4 gv0 = *(const float4*)(g + sl * 8);
    const float4 gv1 = *(const float4*)(g + sl * 8 + 4);
    const float4 bv0 = *(const float4*)(be + sl * 8);
    const float4 bv1 = *(const float4*)(be + sl * 8 + 4);
    float4 o0, o1;
    o0.x = fmaxf(z[0] * rstd * gv0.x + bv0.x, 0.f);
    o0.y = fmaxf(z[1] * rstd * gv0.y + bv0.y, 0.f);
    o0.z = fmaxf(z[2] * rstd * gv0.z + bv0.z, 0.f);
    o0.w = fmaxf(z[3] * rstd * gv0.w + bv0.w, 0.f);
    o1.x = fmaxf(z[4] * rstd * gv1.x + bv1.x, 0.f);
    o1.y = fmaxf(z[5] * rstd * gv1.y + bv1.y, 0.f);
    o1.z = fmaxf(z[6] * rstd * gv1.z + bv1.z, 0.f);
    o1.w = fmaxf(z[7] * rstd * gv1.w + bv1.w, 0.f);
    *(float4*)(out + (size_t)i * OUT_DIM + sl * 8) = o0;
    *(float4*)(out + (size_t)i * OUT_DIM + sl * 8 + 4) = o1;
  }
}

extern "C" void kernel_launch(void* const* d_in, const int* in_sizes, int n_in,
                              void* d_out, int out_size, void* d_ws, size_t ws_size,
                              hipStream_t stream) {
  const float* x       = (const float*)d_in[0];
  const int*   edges   = (const int*)d_in[1];
  const float* Wself0  = (const float*)d_in[2];
  const float* Wneigh0 = (const float*)d_in[3];
  const float* b0      = (const float*)d_in[4];
  const float* g0      = (const float*)d_in[5];
  const float* be0     = (const float*)d_in[6];
  const float* Wself1  = (const float*)d_in[7];
  const float* Wneigh1 = (const float*)d_in[8];
  const float* b1      = (const float*)d_in[9];
  const float* g1      = (const float*)d_in[10];
  const float* be1     = (const float*)d_in[11];

  // ---- 256-byte-aligned workspace carve-out ----
  char* base = (char*)d_ws;
  size_t o = 0;
  auto carve = [&](size_t bytes) {
    char* p = base + o;
    o += (bytes + 255) & ~(size_t)255;
    return p;
  };
  int* flag      = (int*)carve(64 * 4);
  int* gcount    = (int*)carve(1024 * 4);
  int* gbase     = (int*)carve(1024 * 4);
  int* blkbase   = (int*)carve((size_t)NPBLK * NBKT * 4);
  int* deg       = (int*)carve((size_t)N_NODES * 4);
  int* off       = (int*)carve((size_t)N_NODES * 4);
  int* sortedSrc = (int*)carve(1950000 * 4);  // 1.6M + PADCAP*NBKT
  int* pe        = (int*)carve(6500000);      // 1.62M ints; later p1u overlay
  _Float16* B0f  = (_Float16*)carve(128 * 128 * 2);
  unsigned short* B1u = (unsigned short*)carve(64 * 64 * 2);
  unsigned short* p0u = (unsigned short*)carve(((size_t)N_NODES + 2) * HID * 2);
  unsigned short* s0bu = (unsigned short*)carve(((size_t)N_NODES + 2) * HID * 2);
  unsigned short* h1u = (unsigned short*)carve(((size_t)N_NODES + 2) * HID * 2);
  unsigned short* p1u = (unsigned short*)pe;   // overlay (pe dead after csr)
  unsigned short* s1bu = s0bu;                 // overlay (s0bu dead after aggc0)

  hipMemsetAsync(gcount, 0, NBKT * sizeof(int), stream);
  hipMemsetAsync(p0u + (size_t)N_NODES * HID, 0, HID * sizeof(unsigned short),
                 stream);  // zero row for aggc0

  detect_edges<<<1, 256, 0, stream>>>(edges, flag);
  convW<<<80, 256, 0, stream>>>(Wneigh0, Wself0, Wneigh1, Wself1, B0f, B1u);
  g0pc<<<NPBLK + 2 * G0T, 256, 0, stream>>>(x, B0f, b0, p0u, s0bu,
                                            edges, flag, gcount, blkbase);
  part_scan<<<1, 256, 0, stream>>>(gcount, gbase);
  part_scatter<<<NPBLK, 256, 0, stream>>>(edges, flag, gbase, blkbase, pe);
  bucket_csr<<<NBKT, 256, 0, stream>>>(pe, gbase, gcount, deg, off, sortedSrc);

  // pe is dead now; zero p1u's zero-row before aggc1
  hipMemsetAsync(p1u + (size_t)N_NODES * OUT_DIM, 0,
                 OUT_DIM * sizeof(unsigned short), stream);

  aggc0<<<N_NODES / 8, 256, 0, stream>>>(sortedSrc, off, deg, p0u, s0bu,
                                         g0, be0, h1u);
  gemm1<<<(N_NODES + 63) / 64, 256, 0, stream>>>(h1u, B1u, b1, p1u, s1bu);
  aggc1<<<N_NODES / 16, 256, 0, stream>>>(sortedSrc, off, deg, p1u, s1bu,
                                          g1, be1, (float*)d_out);
}

// Round 13
// 155.374 us; speedup vs baseline: 1.1723x; 1.0450x over previous
//
#include <hip/hip_runtime.h>
#include <hip/hip_bf16.h>

#define N_NODES 100000
#define N_EDGES 1600000
#define IN_DIM 128
#define HID 64
#define OUT_DIM 32
#define LN_EPS 1e-5f
#define NBKT 782            // ceil(100000/128) coarse buckets (128 nodes each)
#define NPBLK 500           // partition blocks
#define PAIRS_PER_BLK 1600  // 500*1600*2 = 1.6M edges
#define G0T 1563            // gemm0 row-tiles: ceil(100000/64)
#define PADCAP 384          // max padding per bucket (128 nodes * 3)

typedef __attribute__((ext_vector_type(8))) _Float16 half8;
typedef __attribute__((ext_vector_type(8))) short short8;
typedef __attribute__((ext_vector_type(4))) float f32x4;

__device__ __forceinline__ float uflo(unsigned int u) {
  return __uint_as_float(u << 16);
}
__device__ __forceinline__ float ufhi(unsigned int u) {
  return __uint_as_float(u & 0xffff0000u);
}
__device__ __forceinline__ unsigned short bf16rne(float f) {
  unsigned int u = __float_as_uint(f);
  unsigned int r = u + 0x7fffu + ((u >> 16) & 1u);
  return (unsigned short)(r >> 16);
}
__device__ __forceinline__ unsigned int pk(float lo, float hi) {
  return (unsigned int)bf16rne(lo) | ((unsigned int)bf16rne(hi) << 16);
}

// ---------- Edge dtype detect: int64 (high words all 0) vs int32 ------------
__global__ void detect_edges(const int* __restrict__ w, int* __restrict__ flag) {
  __shared__ int any;
  if (threadIdx.x == 0) any = 0;
  __syncthreads();
  if (w[2 * threadIdx.x + 1] != 0) any = 1;
  __syncthreads();
  if (threadIdx.x == 0) flag[0] = any ? 0 : 1;  // 1 => int64 layout
}

// ---------- Weight convert: B0 fp16 [128n][128k], B1 bf16 [64n][64k] --------
__global__ __launch_bounds__(256) void convW(
    const float* __restrict__ Wn0, const float* __restrict__ Ws0,
    const float* __restrict__ Wn1, const float* __restrict__ Ws1,
    _Float16* __restrict__ B0f, unsigned short* __restrict__ B1u) {
  const int i = blockIdx.x * 256 + threadIdx.x;
  if (i < 128 * 128) {
    const int n = i >> 7, k = i & 127;
    const float w = (n < 64) ? Wn0[k * 64 + n] : Ws0[k * 64 + (n - 64)];
    B0f[i] = (_Float16)w;
  } else if (i < 128 * 128 + 64 * 64) {
    const int j = i - 128 * 128;
    const int n = j >> 6, k = j & 63;
    const float w = (n < 32) ? Wn1[k * 32 + n] : Ws1[k * 32 + (n - 32)];
    B1u[j] = bf16rne(w);
  }
}

// ---------- FUSED: part_count (blocks 0..499) || gemm0 (blocks 500..3625) ---
// part_count now stores its histogram with a PLAIN coalesced store (no
// global atomics — R12's 391K fetch-adds on 25 cache lines serialized the
// whole kernel). Cross-block prefix is computed by bscan afterwards.
__global__ __launch_bounds__(256) void g0pc(
    const float* __restrict__ x, const _Float16* __restrict__ B0f,
    const float* __restrict__ b0,
    unsigned short* __restrict__ p0u, unsigned short* __restrict__ s0bu,
    const int* __restrict__ w, const int* __restrict__ flag,
    int* __restrict__ blkbase) {
  __shared__ _Float16 lb[64 * 128];  // 16 KB (pc path: int hist scratch)
  const int tid = threadIdx.x;

  if (blockIdx.x < NPBLK) {
    // ---------------- part_count path ----------------
    int* h = (int*)lb;
    const int b = blockIdx.x;
    for (int i = tid; i < NBKT; i += 256) h[i] = 0;
    __syncthreads();
    const int i64 = flag[0];
    const int pEnd = (b + 1) * PAIRS_PER_BLK;
    for (int p = b * PAIRS_PER_BLK + tid; p < pEnd; p += 256) {
      int d0, d1;
      if (i64) {
        const int4 vd = *(const int4*)(w + 2 * (size_t)N_EDGES + 4 * (size_t)p);
        d0 = vd.x; d1 = vd.z;
      } else {
        const int2 vd = *(const int2*)(w + (size_t)N_EDGES + 2 * (size_t)p);
        d0 = vd.x; d1 = vd.y;
      }
      atomicAdd(&h[d0 >> 7], 1);
      atomicAdd(&h[d1 >> 7], 1);
    }
    __syncthreads();
    for (int i = tid; i < NBKT; i += 256)
      blkbase[(size_t)b * NBKT + i] = h[i];  // plain coalesced store
    return;
  }

  // ---------------- gemm0 path (64 rows x 64 cols per block) ----------------
  const int gb = blockIdx.x - NPBLK;
  const int colgrp = (gb >= G0T) ? 1 : 0;
  const int rowblk = colgrp ? (gb - G0T) : gb;
  const int lane = tid & 63;
  const int wave = tid >> 6;
  const int rowbase = rowblk * 64 + wave * 16;
  const int arow = rowbase + (lane & 15);
  const int rclamp = (arow < N_NODES) ? arow : 0;
  const int ko = (lane >> 4) << 3;  // 0,8,16,24

  // Prefetch all A (4 k-steps x 32B), independent loads, before staging.
  float av[32];
  {
    const float* ax = x + (size_t)rclamp * IN_DIM + ko;
#pragma unroll
    for (int ks = 0; ks < 4; ++ks) {
      *(float4*)&av[ks * 8] = *(const float4*)(ax + ks * 32);
      *(float4*)&av[ks * 8 + 4] = *(const float4*)(ax + ks * 32 + 4);
    }
  }
  {
    const uint4* gsrc = (const uint4*)(B0f + (colgrp << 13));  // 64*128 halfs
    for (int i = tid; i < 1024; i += 256) {
      const int o = i << 4;
      const int sw = o ^ (((o >> 8) & 7) << 4);
      *(uint4*)((char*)lb + sw) = gsrc[i];
    }
  }
  __syncthreads();

  half8 ah[4];
#pragma unroll
  for (int ks = 0; ks < 4; ++ks) {
#pragma unroll
    for (int j = 0; j < 8; ++j) ah[ks][j] = (_Float16)av[ks * 8 + j];
  }

  f32x4 acc[4];
#pragma unroll
  for (int ct = 0; ct < 4; ++ct) acc[ct] = (f32x4){0.f, 0.f, 0.f, 0.f};

#pragma unroll
  for (int ks = 0; ks < 4; ++ks) {
    const int kb = ks * 64 + (ko << 1);
#pragma unroll
    for (int ct = 0; ct < 4; ++ct) {
      const int n = ct * 16 + (lane & 15);
      const int boff = (n << 8) + kb;
      const int sb = boff ^ (((boff >> 8) & 7) << 4);
      const half8 bv = *(const half8*)((const char*)lb + sb);
      acc[ct] = __builtin_amdgcn_mfma_f32_16x16x32_f16(ah[ks], bv, acc[ct], 0, 0, 0);
    }
  }
  const int rb4 = rowbase + ((lane >> 4) << 2);
  const int cc = lane & 15;
  if (colgrp == 0) {  // -> p0u (bf16)
#pragma unroll
    for (int ct = 0; ct < 4; ++ct) {
#pragma unroll
      for (int j = 0; j < 4; ++j) {
        const int r = rb4 + j;
        if (r < N_NODES) p0u[(size_t)r * HID + ct * 16 + cc] = bf16rne(acc[ct][j]);
      }
    }
  } else {  // -> s0bu (bf16 + bias)
#pragma unroll
    for (int ct = 0; ct < 4; ++ct) {
      const float bias = b0[ct * 16 + cc];
#pragma unroll
      for (int j = 0; j < 4; ++j) {
        const int r = rb4 + j;
        if (r < N_NODES)
          s0bu[(size_t)r * HID + ct * 16 + cc] = bf16rne(acc[ct][j] + bias);
      }
    }
  }
}

// ---------- bscan: per-bucket cross-block exclusive scan (782 blocks) -------
// blkbase[b][i] (counts) -> exclusive prefix along b; bucket total -> gcount.
// Any fixed disjoint-covering assignment is valid (order within a bucket
// region is irrelevant to the final CSR).
__global__ __launch_bounds__(256) void bscan(int* __restrict__ blkbase,
                                             int* __restrict__ gcount) {
  __shared__ int lds[256];
  const int i = blockIdx.x;  // bucket
  const int t = threadIdx.x;
  const int v0 = (t < NPBLK) ? blkbase[(size_t)t * NBKT + i] : 0;
  const int v1 = (t + 256 < NPBLK) ? blkbase[(size_t)(t + 256) * NBKT + i] : 0;
  const int s = v0 + v1;
  lds[t] = s;
  __syncthreads();
  for (int o = 1; o < 256; o <<= 1) {
    const int val = (t >= o) ? lds[t - o] : 0;
    __syncthreads();
    lds[t] += val;
    __syncthreads();
  }
  const int run = lds[t] - s;
  if (t == 255) gcount[i] = lds[255];
  if (t < NPBLK) blkbase[(size_t)t * NBKT + i] = run;
  if (t + 256 < NPBLK) blkbase[(size_t)(t + 256) * NBKT + i] = run + v0;
}

// ---------- Phase B: single-block exclusive scan of 782 bucket counts -------
__global__ __launch_bounds__(256) void part_scan(
    const int* __restrict__ gcount, int* __restrict__ gbase) {
  __shared__ int lds[256];
  const int t = threadIdx.x;
  int v[4];
  int s = 0;
#pragma unroll
  for (int j = 0; j < 4; ++j) {
    const int idx = t * 4 + j;
    v[j] = (idx < NBKT) ? gcount[idx] : 0;
    s += v[j];
  }
  lds[t] = s;
  __syncthreads();
  for (int o = 1; o < 256; o <<= 1) {
    const int val = (t >= o) ? lds[t - o] : 0;
    __syncthreads();
    lds[t] += val;
    __syncthreads();
  }
  int run = lds[t] - s;
#pragma unroll
  for (int j = 0; j < 4; ++j) {
    const int idx = t * 4 + j;
    if (idx < NBKT) gbase[idx] = run;
    run += v[j];
  }
}

// ---------- Phase C: scatter packed edges into coarse-bucket regions --------
// pe[e] = src | (localdst << 17)   (src < 2^17, localdst < 128)
__global__ __launch_bounds__(256) void part_scatter(
    const int* __restrict__ w, const int* __restrict__ flag,
    const int* __restrict__ gbase, const int* __restrict__ blkbase,
    int* __restrict__ pe) {
  __shared__ int cur[NBKT];
  const int t = threadIdx.x, b = blockIdx.x;
  for (int i = t; i < NBKT; i += 256)
    cur[i] = gbase[i] + blkbase[(size_t)b * NBKT + i];
  __syncthreads();
  const int i64 = flag[0];
  const int pEnd = (b + 1) * PAIRS_PER_BLK;
  for (int p = b * PAIRS_PER_BLK + t; p < pEnd; p += 256) {
    int s0, s1, d0, d1;
    if (i64) {
      const int4 vs = *(const int4*)(w + 4 * (size_t)p);
      const int4 vd = *(const int4*)(w + 2 * (size_t)N_EDGES + 4 * (size_t)p);
      s0 = vs.x; s1 = vs.z;
      d0 = vd.x; d1 = vd.z;
    } else {
      const int2 vs = *(const int2*)(w + 2 * (size_t)p);
      const int2 vd = *(const int2*)(w + (size_t)N_EDGES + 2 * (size_t)p);
      s0 = vs.x; s1 = vs.y;
      d0 = vd.x; d1 = vd.y;
    }
    const int sl0 = atomicAdd(&cur[d0 >> 7], 1);
    pe[sl0] = s0 | ((d0 & 127) << 17);
    const int sl1 = atomicAdd(&cur[d1 >> 7], 1);
    pe[sl1] = s1 | ((d1 & 127) << 17);
  }
}

// ---------- Phase D: per-bucket CSR build, padded to x4 with zero-row -------
__global__ __launch_bounds__(256) void bucket_csr(
    const int* __restrict__ pe, const int* __restrict__ gbase,
    const int* __restrict__ gcount, int* __restrict__ deg,
    int* __restrict__ off, int* __restrict__ sortedSrc) {
  __shared__ int ldeg[128];
  __shared__ int loff[128];
  __shared__ int lcur[128];
  const int t = threadIdx.x;
  const int bkt = blockIdx.x;
  const int nbase = bkt << 7;
  const int ebase = gbase[bkt];
  const int cnt = gcount[bkt];
  const int outbase = ebase + PADCAP * bkt;
  if (t < 128) ldeg[t] = 0;
  __syncthreads();
  for (int e = t; e < cnt; e += 256) {
    const int pv = pe[ebase + e];
    atomicAdd(&ldeg[(pv >> 17) & 127], 1);
  }
  __syncthreads();
  if (t < 128) loff[t] = (ldeg[t] + 3) & ~3;  // padded degree
  __syncthreads();
  for (int o = 1; o < 128; o <<= 1) {
    int v = 0;
    if (t >= o && t < 128) v = loff[t - o];
    __syncthreads();
    if (t < 128) loff[t] += v;
    __syncthreads();
  }
  if (t < 128) {
    const int pdeg = (ldeg[t] + 3) & ~3;
    const int ex = loff[t] - pdeg;
    lcur[t] = ex;
    const int n = nbase + t;
    if (n < N_NODES) {
      deg[n] = ldeg[t];
      off[n] = outbase + ex;
    }
  }
  __syncthreads();
  for (int e = t; e < cnt; e += 256) {
    const int pv = pe[ebase + e];
    const int ld = (pv >> 17) & 127;
    const int p = atomicAdd(&lcur[ld], 1);
    sortedSrc[outbase + p] = pv & 0x1FFFF;
  }
  __syncthreads();
  if (t < 128) {
    const int pdeg = (ldeg[t] + 3) & ~3;
    const int ex = loff[t] - pdeg;
    for (int q = ldeg[t]; q < pdeg; ++q)
      sortedSrc[outbase + ex + q] = N_NODES;  // zero row
  }
}

// ------- Layer 1 bf16 MFMA GEMM: [p1 | s1b] = h1 @ [Wn1 | Ws1] (+b1) --------
__global__ __launch_bounds__(256) void gemm1(
    const unsigned short* __restrict__ h1u, const unsigned short* __restrict__ B1u,
    const float* __restrict__ b1,
    unsigned short* __restrict__ p1u, unsigned short* __restrict__ s1bu) {
  __shared__ unsigned short lb[64 * 64];  // 8 KB
  const int tid = threadIdx.x;
  const int lane = tid & 63;
  const int wave = tid >> 6;
  const int rowbase = blockIdx.x * 64 + wave * 16;
  const int arow = rowbase + (lane & 15);
  const int rclamp = (arow < N_NODES) ? arow : 0;
  const int ko = (lane >> 4) << 3;

  short8 ah[2];
  {
    const unsigned short* ax = h1u + (size_t)rclamp * HID + ko;
    ah[0] = *(const short8*)ax;
    ah[1] = *(const short8*)(ax + 32);
  }
  {
    const uint4* gb = (const uint4*)B1u;
    for (int i = tid; i < 512; i += 256) {
      const int o = i << 4;
      const int sw = o ^ (((o >> 7) & 7) << 4);
      *(uint4*)((char*)lb + sw) = gb[i];
    }
  }
  __syncthreads();

  f32x4 acc[4];
#pragma unroll
  for (int ct = 0; ct < 4; ++ct) acc[ct] = (f32x4){0.f, 0.f, 0.f, 0.f};

#pragma unroll
  for (int ks = 0; ks < 2; ++ks) {
    const int kb = ks * 64 + (ko << 1);
#pragma unroll
    for (int ct = 0; ct < 4; ++ct) {
      const int n = ct * 16 + (lane & 15);
      const int boff = (n << 7) + kb;
      const int sb = boff ^ (((boff >> 7) & 7) << 4);
      const short8 bv = *(const short8*)((const char*)lb + sb);
      acc[ct] = __builtin_amdgcn_mfma_f32_16x16x32_bf16(ah[ks], bv, acc[ct], 0, 0, 0);
    }
  }
  const int rb4 = rowbase + ((lane >> 4) << 2);
  const int cc = lane & 15;
#pragma unroll
  for (int ct = 0; ct < 2; ++ct) {  // -> p1 (bf16)
#pragma unroll
    for (int j = 0; j < 4; ++j) {
      const int r = rb4 + j;
      if (r < N_NODES) p1u[(size_t)r * OUT_DIM + ct * 16 + cc] = bf16rne(acc[ct][j]);
    }
  }
#pragma unroll
  for (int ct = 2; ct < 4; ++ct) {  // -> s1bu (bf16 + bias)
#pragma unroll
    for (int j = 0; j < 4; ++j) {
      const int r = rb4 + j;
      if (r < N_NODES)
        s1bu[(size_t)r * OUT_DIM + (ct - 2) * 16 + cc] =
            bf16rne(acc[ct][j] + b1[(ct - 2) * 16 + cc]);
    }
  }
}

// ------- Fused layer-0 aggregate + mean + LN + ReLU -> h1u (2 nodes/wave) ---
__global__ __launch_bounds__(256) void aggc0(
    const int* __restrict__ sortedSrc, const int* __restrict__ off,
    const int* __restrict__ deg, const unsigned short* __restrict__ p0u,
    const unsigned short* __restrict__ s0bu, const float* __restrict__ g,
    const float* __restrict__ be, unsigned short* __restrict__ h1u) {
  const int lane = threadIdx.x & 63;
  const int h = lane >> 5;          // node half
  const int grp = (lane >> 3) & 3;  // 4 edge groups
  const int sl = lane & 7;          // 8 feature slices
  const int i = blockIdx.x * 8 + ((threadIdx.x >> 6) << 1) + h;
  const int st = off[i];
  const int dg = deg[i];
  const int dgp = (dg + 3) & ~3;
  const int dgmaxp = max(dgp, __shfl_xor(dgp, 32));
  float acc[8];
#pragma unroll
  for (int f = 0; f < 8; ++f) acc[f] = 0.f;

  for (int base = 0; base < dgmaxp; base += 32) {
    const int cntp = dgp - base;
    const int l5 = lane & 31;
    const int idx = (l5 < cntp) ? sortedSrc[st + base + l5] : N_NODES;
    const int cm = min(32, dgmaxp - base);  // multiple of 4
    for (int j = 0; j * 4 < cm; ++j) {
      const int e = j * 4 + grp;
      const int srcn = __shfl(idx, (h << 5) | e);
      const uint4 q = *(const uint4*)(p0u + (size_t)srcn * HID + sl * 8);
      acc[0] += uflo(q.x); acc[1] += ufhi(q.x);
      acc[2] += uflo(q.y); acc[3] += ufhi(q.y);
      acc[4] += uflo(q.z); acc[5] += ufhi(q.z);
      acc[6] += uflo(q.w); acc[7] += ufhi(q.w);
    }
  }
  // fold edge groups (xor over lane bits 3,4 — stays within node half)
#pragma unroll
  for (int mk = 8; mk < 32; mk <<= 1) {
#pragma unroll
    for (int f = 0; f < 8; ++f) acc[f] += __shfl_xor(acc[f], mk);
  }
  const float inv = 1.0f / fmaxf((float)dg, 1.0f);
  float z[8];
  const uint4 sbv = *(const uint4*)(s0bu + (size_t)i * HID + sl * 8);
  z[0] = uflo(sbv.x) + acc[0] * inv; z[1] = ufhi(sbv.x) + acc[1] * inv;
  z[2] = uflo(sbv.y) + acc[2] * inv; z[3] = ufhi(sbv.y) + acc[3] * inv;
  z[4] = uflo(sbv.z) + acc[4] * inv; z[5] = ufhi(sbv.z) + acc[5] * inv;
  z[6] = uflo(sbv.w) + acc[6] * inv; z[7] = ufhi(sbv.w) + acc[7] * inv;
  float pm = 0.f;
#pragma unroll
  for (int f = 0; f < 8; ++f) pm += z[f];
#pragma unroll
  for (int mk = 1; mk < 8; mk <<= 1) pm += __shfl_xor(pm, mk);
  const float mean = pm * (1.0f / 64.0f);
  float pv = 0.f;
#pragma unroll
  for (int f = 0; f < 8; ++f) {
    z[f] -= mean;
    pv += z[f] * z[f];
  }
#pragma unroll
  for (int mk = 1; mk < 8; mk <<= 1) pv += __shfl_xor(pv, mk);
  const float rstd = rsqrtf(pv * (1.0f / 64.0f) + LN_EPS);
  if (grp == 0) {
    const float4 gv0 = *(const float4*)(g + sl * 8);
    const float4 gv1 = *(const float4*)(g + sl * 8 + 4);
    const float4 bv0 = *(const float4*)(be + sl * 8);
    const float4 bv1 = *(const float4*)(be + sl * 8 + 4);
    uint4 ov;
    ov.x = pk(fmaxf(z[0] * rstd * gv0.x + bv0.x, 0.f),
              fmaxf(z[1] * rstd * gv0.y + bv0.y, 0.f));
    ov.y = pk(fmaxf(z[2] * rstd * gv0.z + bv0.z, 0.f),
              fmaxf(z[3] * rstd * gv0.w + bv0.w, 0.f));
    ov.z = pk(fmaxf(z[4] * rstd * gv1.x + bv1.x, 0.f),
              fmaxf(z[5] * rstd * gv1.y + bv1.y, 0.f));
    ov.w = pk(fmaxf(z[6] * rstd * gv1.z + bv1.z, 0.f),
              fmaxf(z[7] * rstd * gv1.w + bv1.w, 0.f));
    *(uint4*)(h1u + (size_t)i * HID + sl * 8) = ov;
  }
}

// ------- Fused layer-1 aggregate + mean + LN + ReLU -> out (4 nodes/wave) ---
__global__ __launch_bounds__(256) void aggc1(
    const int* __restrict__ sortedSrc, const int* __restrict__ off,
    const int* __restrict__ deg, const unsigned short* __restrict__ p1u,
    const unsigned short* __restrict__ s1bu, const float* __restrict__ g,
    const float* __restrict__ be, float* __restrict__ out) {
  const int lane = threadIdx.x & 63;
  const int q4 = lane >> 4;         // node quarter
  const int grp = (lane >> 2) & 3;  // 4 edge groups
  const int sl = lane & 3;          // 4 feature slices
  const int i = blockIdx.x * 16 + ((threadIdx.x >> 6) << 2) + q4;
  const int st = off[i];
  const int dg = deg[i];
  const int dgp = (dg + 3) & ~3;
  int dm = max(dgp, __shfl_xor(dgp, 16));
  const int dgmaxp = max(dm, __shfl_xor(dm, 32));
  float acc[8];
#pragma unroll
  for (int f = 0; f < 8; ++f) acc[f] = 0.f;

  for (int base = 0; base < dgmaxp; base += 16) {
    const int cntp = dgp - base;
    const int l4 = lane & 15;
    const int idx = (l4 < cntp) ? sortedSrc[st + base + l4] : N_NODES;
    const int cm = min(16, dgmaxp - base);  // multiple of 4
    for (int j = 0; j * 4 < cm; ++j) {
      const int e = j * 4 + grp;
      const int srcn = __shfl(idx, (q4 << 4) | e);
      const uint4 qv = *(const uint4*)(p1u + (size_t)srcn * OUT_DIM + sl * 8);
      acc[0] += uflo(qv.x); acc[1] += ufhi(qv.x);
      acc[2] += uflo(qv.y); acc[3] += ufhi(qv.y);
      acc[4] += uflo(qv.z); acc[5] += ufhi(qv.z);
      acc[6] += uflo(qv.w); acc[7] += ufhi(qv.w);
    }
  }
  // fold edge groups (xor over lane bits 2,3 — stays within node quarter)
#pragma unroll
  for (int mk = 4; mk < 16; mk <<= 1) {
#pragma unroll
    for (int f = 0; f < 8; ++f) acc[f] += __shfl_xor(acc[f], mk);
  }
  const float inv = 1.0f / fmaxf((float)dg, 1.0f);
  float z[8];
  const uint4 sbv = *(const uint4*)(s1bu + (size_t)i * OUT_DIM + sl * 8);
  z[0] = uflo(sbv.x) + acc[0] * inv; z[1] = ufhi(sbv.x) + acc[1] * inv;
  z[2] = uflo(sbv.y) + acc[2] * inv; z[3] = ufhi(sbv.y) + acc[3] * inv;
  z[4] = uflo(sbv.z) + acc[4] * inv; z[5] = ufhi(sbv.z) + acc[5] * inv;
  z[6] = uflo(sbv.w) + acc[6] * inv; z[7] = ufhi(sbv.w) + acc[7] * inv;
  float pm = 0.f;
#pragma unroll
  for (int f = 0; f < 8; ++f) pm += z[f];
#pragma unroll
  for (int mk = 1; mk < 4; mk <<= 1) pm += __shfl_xor(pm, mk);
  const float mean = pm * (1.0f / 32.0f);
  float pv = 0.f;
#pragma unroll
  for (int f = 0; f < 8; ++f) {
    z[f] -= mean;
    pv += z[f] * z[f];
  }
#pragma unroll
  for (int mk = 1; mk < 4; mk <<= 1) pv += __shfl_xor(pv, mk);
  const float rstd = rsqrtf(pv * (1.0f / 32.0f) + LN_EPS);
  if (grp == 0) {
    const float4 gv0 = *(const float4*)(g + sl * 8);
    const float4 gv1 = *(const float4*)(g + sl * 8 + 4);
    const float4 bv0 = *(const float4*)(be + sl * 8);
    const float4 bv1 = *(const float4*)(be + sl * 8 + 4);
    float4 o0, o1;
    o0.x = fmaxf(z[0] * rstd * gv0.x + bv0.x, 0.f);
    o0.y = fmaxf(z[1] * rstd * gv0.y + bv0.y, 0.f);
    o0.z = fmaxf(z[2] * rstd * gv0.z + bv0.z, 0.f);
    o0.w = fmaxf(z[3] * rstd * gv0.w + bv0.w, 0.f);
    o1.x = fmaxf(z[4] * rstd * gv1.x + bv1.x, 0.f);
    o1.y = fmaxf(z[5] * rstd * gv1.y + bv1.y, 0.f);
    o1.z = fmaxf(z[6] * rstd * gv1.z + bv1.z, 0.f);
    o1.w = fmaxf(z[7] * rstd * gv1.w + bv1.w, 0.f);
    *(float4*)(out + (size_t)i * OUT_DIM + sl * 8) = o0;
    *(float4*)(out + (size_t)i * OUT_DIM + sl * 8 + 4) = o1;
  }
}

extern "C" void kernel_launch(void* const* d_in, const int* in_sizes, int n_in,
                              void* d_out, int out_size, void* d_ws, size_t ws_size,
                              hipStream_t stream) {
  const float* x       = (const float*)d_in[0];
  const int*   edges   = (const int*)d_in[1];
  const float* Wself0  = (const float*)d_in[2];
  const float* Wneigh0 = (const float*)d_in[3];
  const float* b0      = (const float*)d_in[4];
  const float* g0      = (const float*)d_in[5];
  const float* be0     = (const float*)d_in[6];
  const float* Wself1  = (const float*)d_in[7];
  const float* Wneigh1 = (const float*)d_in[8];
  const float* b1      = (const float*)d_in[9];
  const float* g1      = (const float*)d_in[10];
  const float* be1     = (const float*)d_in[11];

  // ---- 256-byte-aligned workspace carve-out ----
  char* base = (char*)d_ws;
  size_t o = 0;
  auto carve = [&](size_t bytes) {
    char* p = base + o;
    o += (bytes + 255) & ~(size_t)255;
    return p;
  };
  int* flag      = (int*)carve(64 * 4);
  int* gcount    = (int*)carve(1024 * 4);
  int* gbase     = (int*)carve(1024 * 4);
  int* blkbase   = (int*)carve((size_t)NPBLK * NBKT * 4);
  int* deg       = (int*)carve((size_t)N_NODES * 4);
  int* off       = (int*)carve((size_t)N_NODES * 4);
  int* sortedSrc = (int*)carve(1950000 * 4);  // 1.6M + PADCAP*NBKT
  int* pe        = (int*)carve(6500000);      // 1.62M ints; later p1u overlay
  _Float16* B0f  = (_Float16*)carve(128 * 128 * 2);
  unsigned short* B1u = (unsigned short*)carve(64 * 64 * 2);
  unsigned short* p0u = (unsigned short*)carve(((size_t)N_NODES + 2) * HID * 2);
  unsigned short* s0bu = (unsigned short*)carve(((size_t)N_NODES + 2) * HID * 2);
  unsigned short* h1u = (unsigned short*)carve(((size_t)N_NODES + 2) * HID * 2);
  unsigned short* p1u = (unsigned short*)pe;   // overlay (pe dead after csr)
  unsigned short* s1bu = s0bu;                 // overlay (s0bu dead after aggc0)

  hipMemsetAsync(p0u + (size_t)N_NODES * HID, 0, HID * sizeof(unsigned short),
                 stream);  // zero row for aggc0

  detect_edges<<<1, 256, 0, stream>>>(edges, flag);
  convW<<<80, 256, 0, stream>>>(Wneigh0, Wself0, Wneigh1, Wself1, B0f, B1u);
  g0pc<<<NPBLK + 2 * G0T, 256, 0, stream>>>(x, B0f, b0, p0u, s0bu,
                                            edges, flag, blkbase);
  bscan<<<NBKT, 256, 0, stream>>>(blkbase, gcount);
  part_scan<<<1, 256, 0, stream>>>(gcount, gbase);
  part_scatter<<<NPBLK, 256, 0, stream>>>(edges, flag, gbase, blkbase, pe);
  bucket_csr<<<NBKT, 256, 0, stream>>>(pe, gbase, gcount, deg, off, sortedSrc);

  // pe is dead now; zero p1u's zero-row before aggc1
  hipMemsetAsync(p1u + (size_t)N_NODES * OUT_DIM, 0,
                 OUT_DIM * sizeof(unsigned short), stream);

  aggc0<<<N_NODES / 8, 256, 0, stream>>>(sortedSrc, off, deg, p0u, s0bu,
                                         g0, be0, h1u);
  gemm1<<<(N_NODES + 63) / 64, 256, 0, stream>>>(h1u, B1u, b1, p1u, s1bu);
  aggc1<<<N_NODES / 16, 256, 0, stream>>>(sortedSrc, off, deg, p1u, s1bu,
                                          g1, be1, (float*)d_out);
}

// Round 14
// 151.917 us; speedup vs baseline: 1.1990x; 1.0228x over previous
//
#include <hip/hip_runtime.h>
#include <hip/hip_bf16.h>

#define N_NODES 100000
#define N_EDGES 1600000
#define IN_DIM 128
#define HID 64
#define OUT_DIM 32
#define LN_EPS 1e-5f
#define NBKT 782            // ceil(100000/128) coarse buckets (128 nodes each)
#define NPBLK 500           // partition blocks
#define PAIRS_PER_BLK 1600  // 500*1600*2 = 1.6M edges
#define G0T 1563            // gemm0 row-tiles: ceil(100000/64)
#define PADCAP 384          // max padding per bucket (128 nodes * 3)

typedef __attribute__((ext_vector_type(8))) _Float16 half8;
typedef __attribute__((ext_vector_type(8))) short short8;
typedef __attribute__((ext_vector_type(4))) float f32x4;

__device__ __forceinline__ float uflo(unsigned int u) {
  return __uint_as_float(u << 16);
}
__device__ __forceinline__ float ufhi(unsigned int u) {
  return __uint_as_float(u & 0xffff0000u);
}
__device__ __forceinline__ unsigned short bf16rne(float f) {
  unsigned int u = __float_as_uint(f);
  unsigned int r = u + 0x7fffu + ((u >> 16) & 1u);
  return (unsigned short)(r >> 16);
}
__device__ __forceinline__ unsigned int pk(float lo, float hi) {
  return (unsigned int)bf16rne(lo) | ((unsigned int)bf16rne(hi) << 16);
}

// ---------- Edge dtype detect + zero-row init (replaces hipMemsetAsync -----
// fills that cost ~41 us each as rocclr fillBuffer dispatches in the graph).
// p1u zero row lives at byte 6.4e6 of the pe region; pe writes exactly
// bytes [0, 6.4e6) (1.6M x 4B), so writing it here (before part_scatter)
// is race-free.
__global__ void detect_edges(const int* __restrict__ w, int* __restrict__ flag,
                             unsigned short* __restrict__ p0u,
                             unsigned short* __restrict__ p1u) {
  __shared__ int any;
  if (threadIdx.x == 0) any = 0;
  __syncthreads();
  if (w[2 * threadIdx.x + 1] != 0) any = 1;
  __syncthreads();
  if (threadIdx.x == 0) flag[0] = any ? 0 : 1;  // 1 => int64 layout
  const int t = threadIdx.x;
  if (t < HID) p0u[(size_t)N_NODES * HID + t] = 0;      // aggc0 zero row
  if (t < OUT_DIM) p1u[(size_t)N_NODES * OUT_DIM + t] = 0;  // aggc1 zero row
}

// ---------- Weight convert: B0 fp16 [128n][128k], B1 bf16 [64n][64k] --------
__global__ __launch_bounds__(256) void convW(
    const float* __restrict__ Wn0, const float* __restrict__ Ws0,
    const float* __restrict__ Wn1, const float* __restrict__ Ws1,
    _Float16* __restrict__ B0f, unsigned short* __restrict__ B1u) {
  const int i = blockIdx.x * 256 + threadIdx.x;
  if (i < 128 * 128) {
    const int n = i >> 7, k = i & 127;
    const float w = (n < 64) ? Wn0[k * 64 + n] : Ws0[k * 64 + (n - 64)];
    B0f[i] = (_Float16)w;
  } else if (i < 128 * 128 + 64 * 64) {
    const int j = i - 128 * 128;
    const int n = j >> 6, k = j & 63;
    const float w = (n < 32) ? Wn1[k * 32 + n] : Ws1[k * 32 + (n - 32)];
    B1u[j] = bf16rne(w);
  }
}

// ---------- FUSED: part_count (blocks 0..499) || gemm0 (blocks 500..3625) ---
__global__ __launch_bounds__(256) void g0pc(
    const float* __restrict__ x, const _Float16* __restrict__ B0f,
    const float* __restrict__ b0,
    unsigned short* __restrict__ p0u, unsigned short* __restrict__ s0bu,
    const int* __restrict__ w, const int* __restrict__ flag,
    int* __restrict__ blkbase) {
  __shared__ _Float16 lb[64 * 128];  // 16 KB (pc path: int hist scratch)
  const int tid = threadIdx.x;

  if (blockIdx.x < NPBLK) {
    // ---------------- part_count path ----------------
    int* h = (int*)lb;
    const int b = blockIdx.x;
    for (int i = tid; i < NBKT; i += 256) h[i] = 0;
    __syncthreads();
    const int i64 = flag[0];
    const int pEnd = (b + 1) * PAIRS_PER_BLK;
    for (int p = b * PAIRS_PER_BLK + tid; p < pEnd; p += 256) {
      int d0, d1;
      if (i64) {
        const int4 vd = *(const int4*)(w + 2 * (size_t)N_EDGES + 4 * (size_t)p);
        d0 = vd.x; d1 = vd.z;
      } else {
        const int2 vd = *(const int2*)(w + (size_t)N_EDGES + 2 * (size_t)p);
        d0 = vd.x; d1 = vd.y;
      }
      atomicAdd(&h[d0 >> 7], 1);
      atomicAdd(&h[d1 >> 7], 1);
    }
    __syncthreads();
    for (int i = tid; i < NBKT; i += 256)
      blkbase[(size_t)b * NBKT + i] = h[i];  // plain coalesced store
    return;
  }

  // ---------------- gemm0 path (64 rows x 64 cols per block) ----------------
  const int gb = blockIdx.x - NPBLK;
  const int colgrp = (gb >= G0T) ? 1 : 0;
  const int rowblk = colgrp ? (gb - G0T) : gb;
  const int lane = tid & 63;
  const int wave = tid >> 6;
  const int rowbase = rowblk * 64 + wave * 16;
  const int arow = rowbase + (lane & 15);
  const int rclamp = (arow < N_NODES) ? arow : 0;
  const int ko = (lane >> 4) << 3;  // 0,8,16,24

  // Prefetch all A (4 k-steps x 32B), independent loads, before staging.
  float av[32];
  {
    const float* ax = x + (size_t)rclamp * IN_DIM + ko;
#pragma unroll
    for (int ks = 0; ks < 4; ++ks) {
      *(float4*)&av[ks * 8] = *(const float4*)(ax + ks * 32);
      *(float4*)&av[ks * 8 + 4] = *(const float4*)(ax + ks * 32 + 4);
    }
  }
  {
    const uint4* gsrc = (const uint4*)(B0f + (colgrp << 13));  // 64*128 halfs
    for (int i = tid; i < 1024; i += 256) {
      const int o = i << 4;
      const int sw = o ^ (((o >> 8) & 7) << 4);
      *(uint4*)((char*)lb + sw) = gsrc[i];
    }
  }
  __syncthreads();

  half8 ah[4];
#pragma unroll
  for (int ks = 0; ks < 4; ++ks) {
#pragma unroll
    for (int j = 0; j < 8; ++j) ah[ks][j] = (_Float16)av[ks * 8 + j];
  }

  f32x4 acc[4];
#pragma unroll
  for (int ct = 0; ct < 4; ++ct) acc[ct] = (f32x4){0.f, 0.f, 0.f, 0.f};

#pragma unroll
  for (int ks = 0; ks < 4; ++ks) {
    const int kb = ks * 64 + (ko << 1);
#pragma unroll
    for (int ct = 0; ct < 4; ++ct) {
      const int n = ct * 16 + (lane & 15);
      const int boff = (n << 8) + kb;
      const int sb = boff ^ (((boff >> 8) & 7) << 4);
      const half8 bv = *(const half8*)((const char*)lb + sb);
      acc[ct] = __builtin_amdgcn_mfma_f32_16x16x32_f16(ah[ks], bv, acc[ct], 0, 0, 0);
    }
  }
  const int rb4 = rowbase + ((lane >> 4) << 2);
  const int cc = lane & 15;
  if (colgrp == 0) {  // -> p0u (bf16)
#pragma unroll
    for (int ct = 0; ct < 4; ++ct) {
#pragma unroll
      for (int j = 0; j < 4; ++j) {
        const int r = rb4 + j;
        if (r < N_NODES) p0u[(size_t)r * HID + ct * 16 + cc] = bf16rne(acc[ct][j]);
      }
    }
  } else {  // -> s0bu (bf16 + bias)
#pragma unroll
    for (int ct = 0; ct < 4; ++ct) {
      const float bias = b0[ct * 16 + cc];
#pragma unroll
      for (int j = 0; j < 4; ++j) {
        const int r = rb4 + j;
        if (r < N_NODES)
          s0bu[(size_t)r * HID + ct * 16 + cc] = bf16rne(acc[ct][j] + bias);
      }
    }
  }
}

// ---------- bscan: per-bucket cross-block exclusive scan (782 blocks) -------
__global__ __launch_bounds__(256) void bscan(int* __restrict__ blkbase,
                                             int* __restrict__ gcount) {
  __shared__ int lds[256];
  const int i = blockIdx.x;  // bucket
  const int t = threadIdx.x;
  const int v0 = (t < NPBLK) ? blkbase[(size_t)t * NBKT + i] : 0;
  const int v1 = (t + 256 < NPBLK) ? blkbase[(size_t)(t + 256) * NBKT + i] : 0;
  const int s = v0 + v1;
  lds[t] = s;
  __syncthreads();
  for (int o = 1; o < 256; o <<= 1) {
    const int val = (t >= o) ? lds[t - o] : 0;
    __syncthreads();
    lds[t] += val;
    __syncthreads();
  }
  const int run = lds[t] - s;
  if (t == 255) gcount[i] = lds[255];
  if (t < NPBLK) blkbase[(size_t)t * NBKT + i] = run;
  if (t + 256 < NPBLK) blkbase[(size_t)(t + 256) * NBKT + i] = run + v0;
}

// ---------- Phase B: single-block exclusive scan of 782 bucket counts -------
__global__ __launch_bounds__(256) void part_scan(
    const int* __restrict__ gcount, int* __restrict__ gbase) {
  __shared__ int lds[256];
  const int t = threadIdx.x;
  int v[4];
  int s = 0;
#pragma unroll
  for (int j = 0; j < 4; ++j) {
    const int idx = t * 4 + j;
    v[j] = (idx < NBKT) ? gcount[idx] : 0;
    s += v[j];
  }
  lds[t] = s;
  __syncthreads();
  for (int o = 1; o < 256; o <<= 1) {
    const int val = (t >= o) ? lds[t - o] : 0;
    __syncthreads();
    lds[t] += val;
    __syncthreads();
  }
  int run = lds[t] - s;
#pragma unroll
  for (int j = 0; j < 4; ++j) {
    const int idx = t * 4 + j;
    if (idx < NBKT) gbase[idx] = run;
    run += v[j];
  }
}

// ---------- Phase C: scatter packed edges into coarse-bucket regions --------
// pe[e] = src | (localdst << 17)   (src < 2^17, localdst < 128)
__global__ __launch_bounds__(256) void part_scatter(
    const int* __restrict__ w, const int* __restrict__ flag,
    const int* __restrict__ gbase, const int* __restrict__ blkbase,
    int* __restrict__ pe) {
  __shared__ int cur[NBKT];
  const int t = threadIdx.x, b = blockIdx.x;
  for (int i = t; i < NBKT; i += 256)
    cur[i] = gbase[i] + blkbase[(size_t)b * NBKT + i];
  __syncthreads();
  const int i64 = flag[0];
  const int pEnd = (b + 1) * PAIRS_PER_BLK;
  for (int p = b * PAIRS_PER_BLK + t; p < pEnd; p += 256) {
    int s0, s1, d0, d1;
    if (i64) {
      const int4 vs = *(const int4*)(w + 4 * (size_t)p);
      const int4 vd = *(const int4*)(w + 2 * (size_t)N_EDGES + 4 * (size_t)p);
      s0 = vs.x; s1 = vs.z;
      d0 = vd.x; d1 = vd.z;
    } else {
      const int2 vs = *(const int2*)(w + 2 * (size_t)p);
      const int2 vd = *(const int2*)(w + (size_t)N_EDGES + 2 * (size_t)p);
      s0 = vs.x; s1 = vs.y;
      d0 = vd.x; d1 = vd.y;
    }
    const int sl0 = atomicAdd(&cur[d0 >> 7], 1);
    pe[sl0] = s0 | ((d0 & 127) << 17);
    const int sl1 = atomicAdd(&cur[d1 >> 7], 1);
    pe[sl1] = s1 | ((d1 & 127) << 17);
  }
}

// ---------- Phase D: per-bucket CSR build, padded to x4 with zero-row -------
__global__ __launch_bounds__(256) void bucket_csr(
    const int* __restrict__ pe, const int* __restrict__ gbase,
    const int* __restrict__ gcount, int* __restrict__ deg,
    int* __restrict__ off, int* __restrict__ sortedSrc) {
  __shared__ int ldeg[128];
  __shared__ int loff[128];
  __shared__ int lcur[128];
  const int t = threadIdx.x;
  const int bkt = blockIdx.x;
  const int nbase = bkt << 7;
  const int ebase = gbase[bkt];
  const int cnt = gcount[bkt];
  const int outbase = ebase + PADCAP * bkt;
  if (t < 128) ldeg[t] = 0;
  __syncthreads();
  for (int e = t; e < cnt; e += 256) {
    const int pv = pe[ebase + e];
    atomicAdd(&ldeg[(pv >> 17) & 127], 1);
  }
  __syncthreads();
  if (t < 128) loff[t] = (ldeg[t] + 3) & ~3;  // padded degree
  __syncthreads();
  for (int o = 1; o < 128; o <<= 1) {
    int v = 0;
    if (t >= o && t < 128) v = loff[t - o];
    __syncthreads();
    if (t < 128) loff[t] += v;
    __syncthreads();
  }
  if (t < 128) {
    const int pdeg = (ldeg[t] + 3) & ~3;
    const int ex = loff[t] - pdeg;
    lcur[t] = ex;
    const int n = nbase + t;
    if (n < N_NODES) {
      deg[n] = ldeg[t];
      off[n] = outbase + ex;
    }
  }
  __syncthreads();
  for (int e = t; e < cnt; e += 256) {
    const int pv = pe[ebase + e];
    const int ld = (pv >> 17) & 127;
    const int p = atomicAdd(&lcur[ld], 1);
    sortedSrc[outbase + p] = pv & 0x1FFFF;
  }
  __syncthreads();
  if (t < 128) {
    const int pdeg = (ldeg[t] + 3) & ~3;
    const int ex = loff[t] - pdeg;
    for (int q = ldeg[t]; q < pdeg; ++q)
      sortedSrc[outbase + ex + q] = N_NODES;  // zero row
  }
}

// ------- Layer 1 bf16 MFMA GEMM: [p1 | s1b] = h1 @ [Wn1 | Ws1] (+b1) --------
__global__ __launch_bounds__(256) void gemm1(
    const unsigned short* __restrict__ h1u, const unsigned short* __restrict__ B1u,
    const float* __restrict__ b1,
    unsigned short* __restrict__ p1u, unsigned short* __restrict__ s1bu) {
  __shared__ unsigned short lb[64 * 64];  // 8 KB
  const int tid = threadIdx.x;
  const int lane = tid & 63;
  const int wave = tid >> 6;
  const int rowbase = blockIdx.x * 64 + wave * 16;
  const int arow = rowbase + (lane & 15);
  const int rclamp = (arow < N_NODES) ? arow : 0;
  const int ko = (lane >> 4) << 3;

  short8 ah[2];
  {
    const unsigned short* ax = h1u + (size_t)rclamp * HID + ko;
    ah[0] = *(const short8*)ax;
    ah[1] = *(const short8*)(ax + 32);
  }
  {
    const uint4* gb = (const uint4*)B1u;
    for (int i = tid; i < 512; i += 256) {
      const int o = i << 4;
      const int sw = o ^ (((o >> 7) & 7) << 4);
      *(uint4*)((char*)lb + sw) = gb[i];
    }
  }
  __syncthreads();

  f32x4 acc[4];
#pragma unroll
  for (int ct = 0; ct < 4; ++ct) acc[ct] = (f32x4){0.f, 0.f, 0.f, 0.f};

#pragma unroll
  for (int ks = 0; ks < 2; ++ks) {
    const int kb = ks * 64 + (ko << 1);
#pragma unroll
    for (int ct = 0; ct < 4; ++ct) {
      const int n = ct * 16 + (lane & 15);
      const int boff = (n << 7) + kb;
      const int sb = boff ^ (((boff >> 7) & 7) << 4);
      const short8 bv = *(const short8*)((const char*)lb + sb);
      acc[ct] = __builtin_amdgcn_mfma_f32_16x16x32_bf16(ah[ks], bv, acc[ct], 0, 0, 0);
    }
  }
  const int rb4 = rowbase + ((lane >> 4) << 2);
  const int cc = lane & 15;
#pragma unroll
  for (int ct = 0; ct < 2; ++ct) {  // -> p1 (bf16)
#pragma unroll
    for (int j = 0; j < 4; ++j) {
      const int r = rb4 + j;
      if (r < N_NODES) p1u[(size_t)r * OUT_DIM + ct * 16 + cc] = bf16rne(acc[ct][j]);
    }
  }
#pragma unroll
  for (int ct = 2; ct < 4; ++ct) {  // -> s1bu (bf16 + bias)
#pragma unroll
    for (int j = 0; j < 4; ++j) {
      const int r = rb4 + j;
      if (r < N_NODES)
        s1bu[(size_t)r * OUT_DIM + (ct - 2) * 16 + cc] =
            bf16rne(acc[ct][j] + b1[(ct - 2) * 16 + cc]);
    }
  }
}

// ------- Fused layer-0 aggregate + mean + LN + ReLU -> h1u (2 nodes/wave) ---
__global__ __launch_bounds__(256) void aggc0(
    const int* __restrict__ sortedSrc, const int* __restrict__ off,
    const int* __restrict__ deg, const unsigned short* __restrict__ p0u,
    const unsigned short* __restrict__ s0bu, const float* __restrict__ g,
    const float* __restrict__ be, unsigned short* __restrict__ h1u) {
  const int lane = threadIdx.x & 63;
  const int h = lane >> 5;          // node half
  const int grp = (lane >> 3) & 3;  // 4 edge groups
  const int sl = lane & 7;          // 8 feature slices
  const int i = blockIdx.x * 8 + ((threadIdx.x >> 6) << 1) + h;
  const int st = off[i];
  const int dg = deg[i];
  const int dgp = (dg + 3) & ~3;
  const int dgmaxp = max(dgp, __shfl_xor(dgp, 32));
  float acc[8];
#pragma unroll
  for (int f = 0; f < 8; ++f) acc[f] = 0.f;

  for (int base = 0; base < dgmaxp; base += 32) {
    const int cntp = dgp - base;
    const int l5 = lane & 31;
    const int idx = (l5 < cntp) ? sortedSrc[st + base + l5] : N_NODES;
    const int cm = min(32, dgmaxp - base);  // multiple of 4
    for (int j = 0; j * 4 < cm; ++j) {
      const int e = j * 4 + grp;
      const int srcn = __shfl(idx, (h << 5) | e);
      const uint4 q = *(const uint4*)(p0u + (size_t)srcn * HID + sl * 8);
      acc[0] += uflo(q.x); acc[1] += ufhi(q.x);
      acc[2] += uflo(q.y); acc[3] += ufhi(q.y);
      acc[4] += uflo(q.z); acc[5] += ufhi(q.z);
      acc[6] += uflo(q.w); acc[7] += ufhi(q.w);
    }
  }
  // fold edge groups (xor over lane bits 3,4 — stays within node half)
#pragma unroll
  for (int mk = 8; mk < 32; mk <<= 1) {
#pragma unroll
    for (int f = 0; f < 8; ++f) acc[f] += __shfl_xor(acc[f], mk);
  }
  const float inv = 1.0f / fmaxf((float)dg, 1.0f);
  float z[8];
  const uint4 sbv = *(const uint4*)(s0bu + (size_t)i * HID + sl * 8);
  z[0] = uflo(sbv.x) + acc[0] * inv; z[1] = ufhi(sbv.x) + acc[1] * inv;
  z[2] = uflo(sbv.y) + acc[2] * inv; z[3] = ufhi(sbv.y) + acc[3] * inv;
  z[4] = uflo(sbv.z) + acc[4] * inv; z[5] = ufhi(sbv.z) + acc[5] * inv;
  z[6] = uflo(sbv.w) + acc[6] * inv; z[7] = ufhi(sbv.w) + acc[7] * inv;
  float pm = 0.f;
#pragma unroll
  for (int f = 0; f < 8; ++f) pm += z[f];
#pragma unroll
  for (int mk = 1; mk < 8; mk <<= 1) pm += __shfl_xor(pm, mk);
  const float mean = pm * (1.0f / 64.0f);
  float pv = 0.f;
#pragma unroll
  for (int f = 0; f < 8; ++f) {
    z[f] -= mean;
    pv += z[f] * z[f];
  }
#pragma unroll
  for (int mk = 1; mk < 8; mk <<= 1) pv += __shfl_xor(pv, mk);
  const float rstd = rsqrtf(pv * (1.0f / 64.0f) + LN_EPS);
  if (grp == 0) {
    const float4 gv0 = *(const float4*)(g + sl * 8);
    const float4 gv1 = *(const float4*)(g + sl * 8 + 4);
    const float4 bv0 = *(const float4*)(be + sl * 8);
    const float4 bv1 = *(const float4*)(be + sl * 8 + 4);
    uint4 ov;
    ov.x = pk(fmaxf(z[0] * rstd * gv0.x + bv0.x, 0.f),
              fmaxf(z[1] * rstd * gv0.y + bv0.y, 0.f));
    ov.y = pk(fmaxf(z[2] * rstd * gv0.z + bv0.z, 0.f),
              fmaxf(z[3] * rstd * gv0.w + bv0.w, 0.f));
    ov.z = pk(fmaxf(z[4] * rstd * gv1.x + bv1.x, 0.f),
              fmaxf(z[5] * rstd * gv1.y + bv1.y, 0.f));
    ov.w = pk(fmaxf(z[6] * rstd * gv1.z + bv1.z, 0.f),
              fmaxf(z[7] * rstd * gv1.w + bv1.w, 0.f));
    *(uint4*)(h1u + (size_t)i * HID + sl * 8) = ov;
  }
}

// ------- Fused layer-1 aggregate + mean + LN + ReLU -> out (4 nodes/wave) ---
__global__ __launch_bounds__(256) void aggc1(
    const int* __restrict__ sortedSrc, const int* __restrict__ off,
    const int* __restrict__ deg, const unsigned short* __restrict__ p1u,
    const unsigned short* __restrict__ s1bu, const float* __restrict__ g,
    const float* __restrict__ be, float* __restrict__ out) {
  const int lane = threadIdx.x & 63;
  const int q4 = lane >> 4;         // node quarter
  const int grp = (lane >> 2) & 3;  // 4 edge groups
  const int sl = lane & 3;          // 4 feature slices
  const int i = blockIdx.x * 16 + ((threadIdx.x >> 6) << 2) + q4;
  const int st = off[i];
  const int dg = deg[i];
  const int dgp = (dg + 3) & ~3;
  int dm = max(dgp, __shfl_xor(dgp, 16));
  const int dgmaxp = max(dm, __shfl_xor(dm, 32));
  float acc[8];
#pragma unroll
  for (int f = 0; f < 8; ++f) acc[f] = 0.f;

  for (int base = 0; base < dgmaxp; base += 16) {
    const int cntp = dgp - base;
    const int l4 = lane & 15;
    const int idx = (l4 < cntp) ? sortedSrc[st + base + l4] : N_NODES;
    const int cm = min(16, dgmaxp - base);  // multiple of 4
    for (int j = 0; j * 4 < cm; ++j) {
      const int e = j * 4 + grp;
      const int srcn = __shfl(idx, (q4 << 4) | e);
      const uint4 qv = *(const uint4*)(p1u + (size_t)srcn * OUT_DIM + sl * 8);
      acc[0] += uflo(qv.x); acc[1] += ufhi(qv.x);
      acc[2] += uflo(qv.y); acc[3] += ufhi(qv.y);
      acc[4] += uflo(qv.z); acc[5] += ufhi(qv.z);
      acc[6] += uflo(qv.w); acc[7] += ufhi(qv.w);
    }
  }
  // fold edge groups (xor over lane bits 2,3 — stays within node quarter)
#pragma unroll
  for (int mk = 4; mk < 16; mk <<= 1) {
#pragma unroll
    for (int f = 0; f < 8; ++f) acc[f] += __shfl_xor(acc[f], mk);
  }
  const float inv = 1.0f / fmaxf((float)dg, 1.0f);
  float z[8];
  const uint4 sbv = *(const uint4*)(s1bu + (size_t)i * OUT_DIM + sl * 8);
  z[0] = uflo(sbv.x) + acc[0] * inv; z[1] = ufhi(sbv.x) + acc[1] * inv;
  z[2] = uflo(sbv.y) + acc[2] * inv; z[3] = ufhi(sbv.y) + acc[3] * inv;
  z[4] = uflo(sbv.z) + acc[4] * inv; z[5] = ufhi(sbv.z) + acc[5] * inv;
  z[6] = uflo(sbv.w) + acc[6] * inv; z[7] = ufhi(sbv.w) + acc[7] * inv;
  float pm = 0.f;
#pragma unroll
  for (int f = 0; f < 8; ++f) pm += z[f];
#pragma unroll
  for (int mk = 1; mk < 4; mk <<= 1) pm += __shfl_xor(pm, mk);
  const float mean = pm * (1.0f / 32.0f);
  float pv = 0.f;
#pragma unroll
  for (int f = 0; f < 8; ++f) {
    z[f] -= mean;
    pv += z[f] * z[f];
  }
#pragma unroll
  for (int mk = 1; mk < 4; mk <<= 1) pv += __shfl_xor(pv, mk);
  const float rstd = rsqrtf(pv * (1.0f / 32.0f) + LN_EPS);
  if (grp == 0) {
    const float4 gv0 = *(const float4*)(g + sl * 8);
    const float4 gv1 = *(const float4*)(g + sl * 8 + 4);
    const float4 bv0 = *(const float4*)(be + sl * 8);
    const float4 bv1 = *(const float4*)(be + sl * 8 + 4);
    float4 o0, o1;
    o0.x = fmaxf(z[0] * rstd * gv0.x + bv0.x, 0.f);
    o0.y = fmaxf(z[1] * rstd * gv0.y + bv0.y, 0.f);
    o0.z = fmaxf(z[2] * rstd * gv0.z + bv0.z, 0.f);
    o0.w = fmaxf(z[3] * rstd * gv0.w + bv0.w, 0.f);
    o1.x = fmaxf(z[4] * rstd * gv1.x + bv1.x, 0.f);
    o1.y = fmaxf(z[5] * rstd * gv1.y + bv1.y, 0.f);
    o1.z = fmaxf(z[6] * rstd * gv1.z + bv1.z, 0.f);
    o1.w = fmaxf(z[7] * rstd * gv1.w + bv1.w, 0.f);
    *(float4*)(out + (size_t)i * OUT_DIM + sl * 8) = o0;
    *(float4*)(out + (size_t)i * OUT_DIM + sl * 8 + 4) = o1;
  }
}

extern "C" void kernel_launch(void* const* d_in, const int* in_sizes, int n_in,
                              void* d_out, int out_size, void* d_ws, size_t ws_size,
                              hipStream_t stream) {
  const float* x       = (const float*)d_in[0];
  const int*   edges   = (const int*)d_in[1];
  const float* Wself0  = (const float*)d_in[2];
  const float* Wneigh0 = (const float*)d_in[3];
  const float* b0      = (const float*)d_in[4];
  const float* g0      = (const float*)d_in[5];
  const float* be0     = (const float*)d_in[6];
  const float* Wself1  = (const float*)d_in[7];
  const float* Wneigh1 = (const float*)d_in[8];
  const float* b1      = (const float*)d_in[9];
  const float* g1      = (const float*)d_in[10];
  const float* be1     = (const float*)d_in[11];

  // ---- 256-byte-aligned workspace carve-out ----
  char* base = (char*)d_ws;
  size_t o = 0;
  auto carve = [&](size_t bytes) {
    char* p = base + o;
    o += (bytes + 255) & ~(size_t)255;
    return p;
  };
  int* flag      = (int*)carve(64 * 4);
  int* gcount    = (int*)carve(1024 * 4);
  int* gbase     = (int*)carve(1024 * 4);
  int* blkbase   = (int*)carve((size_t)NPBLK * NBKT * 4);
  int* deg       = (int*)carve((size_t)N_NODES * 4);
  int* off       = (int*)carve((size_t)N_NODES * 4);
  int* sortedSrc = (int*)carve(1950000 * 4);  // 1.6M + PADCAP*NBKT
  int* pe        = (int*)carve(6500000);      // 1.62M ints; later p1u overlay
  _Float16* B0f  = (_Float16*)carve(128 * 128 * 2);
  unsigned short* B1u = (unsigned short*)carve(64 * 64 * 2);
  unsigned short* p0u = (unsigned short*)carve(((size_t)N_NODES + 2) * HID * 2);
  unsigned short* s0bu = (unsigned short*)carve(((size_t)N_NODES + 2) * HID * 2);
  unsigned short* h1u = (unsigned short*)carve(((size_t)N_NODES + 2) * HID * 2);
  unsigned short* p1u = (unsigned short*)pe;   // overlay (pe dead after csr)
  unsigned short* s1bu = s0bu;                 // overlay (s0bu dead after aggc0)

  detect_edges<<<1, 256, 0, stream>>>(edges, flag, p0u, p1u);
  convW<<<80, 256, 0, stream>>>(Wneigh0, Wself0, Wneigh1, Wself1, B0f, B1u);
  g0pc<<<NPBLK + 2 * G0T, 256, 0, stream>>>(x, B0f, b0, p0u, s0bu,
                                            edges, flag, blkbase);
  bscan<<<NBKT, 256, 0, stream>>>(blkbase, gcount);
  part_scan<<<1, 256, 0, stream>>>(gcount, gbase);
  part_scatter<<<NPBLK, 256, 0, stream>>>(edges, flag, gbase, blkbase, pe);
  bucket_csr<<<NBKT, 256, 0, stream>>>(pe, gbase, gcount, deg, off, sortedSrc);

  aggc0<<<N_NODES / 8, 256, 0, stream>>>(sortedSrc, off, deg, p0u, s0bu,
                                         g0, be0, h1u);
  gemm1<<<(N_NODES + 63) / 64, 256, 0, stream>>>(h1u, B1u, b1, p1u, s1bu);
  aggc1<<<N_NODES / 16, 256, 0, stream>>>(sortedSrc, off, deg, p1u, s1bu,
                                          g1, be1, (float*)d_out);
}

// Round 15
// 151.033 us; speedup vs baseline: 1.2060x; 1.0059x over previous
//
#include <hip/hip_runtime.h>
#include <hip/hip_bf16.h>

#define N_NODES 100000
#define N_EDGES 1600000
#define IN_DIM 128
#define HID 64
#define OUT_DIM 32
#define LN_EPS 1e-5f
#define NBKT 782            // ceil(100000/128) coarse buckets (128 nodes each)
#define NPBLK 500           // partition blocks
#define PAIRS_PER_BLK 1600  // 500*1600*2 = 1.6M edges
#define G0T 1563            // gemm0 row-tiles: ceil(100000/64)
#define PADCAP 384          // max padding per bucket (128 nodes * 3)

typedef __attribute__((ext_vector_type(8))) _Float16 half8;
typedef __attribute__((ext_vector_type(8))) short short8;
typedef __attribute__((ext_vector_type(4))) float f32x4;

__device__ __forceinline__ float uflo(unsigned int u) {
  return __uint_as_float(u << 16);
}
__device__ __forceinline__ float ufhi(unsigned int u) {
  return __uint_as_float(u & 0xffff0000u);
}
__device__ __forceinline__ unsigned short bf16rne(float f) {
  unsigned int u = __float_as_uint(f);
  unsigned int r = u + 0x7fffu + ((u >> 16) & 1u);
  return (unsigned short)(r >> 16);
}
__device__ __forceinline__ unsigned int pk(float lo, float hi) {
  return (unsigned int)bf16rne(lo) | ((unsigned int)bf16rne(hi) << 16);
}

// ---------- Edge dtype detect + zero-row init -------------------------------
__global__ void detect_edges(const int* __restrict__ w, int* __restrict__ flag,
                             unsigned short* __restrict__ p0u,
                             unsigned short* __restrict__ p1u) {
  __shared__ int any;
  if (threadIdx.x == 0) any = 0;
  __syncthreads();
  if (w[2 * threadIdx.x + 1] != 0) any = 1;
  __syncthreads();
  if (threadIdx.x == 0) flag[0] = any ? 0 : 1;  // 1 => int64 layout
  const int t = threadIdx.x;
  if (t < HID) p0u[(size_t)N_NODES * HID + t] = 0;          // aggc0 zero row
  if (t < OUT_DIM) p1u[(size_t)N_NODES * OUT_DIM + t] = 0;  // aggc1 zero row
}

// ---------- Weight convert: B0 fp16 [128n][128k], B1 bf16 [64n][64k] --------
__global__ __launch_bounds__(256) void convW(
    const float* __restrict__ Wn0, const float* __restrict__ Ws0,
    const float* __restrict__ Wn1, const float* __restrict__ Ws1,
    _Float16* __restrict__ B0f, unsigned short* __restrict__ B1u) {
  const int i = blockIdx.x * 256 + threadIdx.x;
  if (i < 128 * 128) {
    const int n = i >> 7, k = i & 127;
    const float w = (n < 64) ? Wn0[k * 64 + n] : Ws0[k * 64 + (n - 64)];
    B0f[i] = (_Float16)w;
  } else if (i < 128 * 128 + 64 * 64) {
    const int j = i - 128 * 128;
    const int n = j >> 6, k = j & 63;
    const float w = (n < 32) ? Wn1[k * 32 + n] : Ws1[k * 32 + (n - 32)];
    B1u[j] = bf16rne(w);
  }
}

// ---------- gemm0 body: 64 rows x 64 cols, one column-group -----------------
__device__ __forceinline__ void gemm0_body(
    int rowblk, int colgrp, int tid, _Float16* lb,
    const float* __restrict__ x, const _Float16* __restrict__ B0f,
    const float* __restrict__ b0, unsigned short* __restrict__ p0u,
    unsigned short* __restrict__ s0bu) {
  const int lane = tid & 63;
  const int wave = tid >> 6;
  const int rowbase = rowblk * 64 + wave * 16;
  const int arow = rowbase + (lane & 15);
  const int rclamp = (arow < N_NODES) ? arow : 0;
  const int ko = (lane >> 4) << 3;  // 0,8,16,24

  float av[32];
  {
    const float* ax = x + (size_t)rclamp * IN_DIM + ko;
#pragma unroll
    for (int ks = 0; ks < 4; ++ks) {
      *(float4*)&av[ks * 8] = *(const float4*)(ax + ks * 32);
      *(float4*)&av[ks * 8 + 4] = *(const float4*)(ax + ks * 32 + 4);
    }
  }
  {
    const uint4* gsrc = (const uint4*)(B0f + (colgrp << 13));  // 64*128 halfs
    for (int i = tid; i < 1024; i += 256) {
      const int o = i << 4;
      const int sw = o ^ (((o >> 8) & 7) << 4);
      *(uint4*)((char*)lb + sw) = gsrc[i];
    }
  }
  __syncthreads();

  half8 ah[4];
#pragma unroll
  for (int ks = 0; ks < 4; ++ks) {
#pragma unroll
    for (int j = 0; j < 8; ++j) ah[ks][j] = (_Float16)av[ks * 8 + j];
  }

  f32x4 acc[4];
#pragma unroll
  for (int ct = 0; ct < 4; ++ct) acc[ct] = (f32x4){0.f, 0.f, 0.f, 0.f};

#pragma unroll
  for (int ks = 0; ks < 4; ++ks) {
    const int kb = ks * 64 + (ko << 1);
#pragma unroll
    for (int ct = 0; ct < 4; ++ct) {
      const int n = ct * 16 + (lane & 15);
      const int boff = (n << 8) + kb;
      const int sb = boff ^ (((boff >> 8) & 7) << 4);
      const half8 bv = *(const half8*)((const char*)lb + sb);
      acc[ct] = __builtin_amdgcn_mfma_f32_16x16x32_f16(ah[ks], bv, acc[ct], 0, 0, 0);
    }
  }
  const int rb4 = rowbase + ((lane >> 4) << 2);
  const int cc = lane & 15;
  if (colgrp == 0) {  // -> p0u (bf16)
#pragma unroll
    for (int ct = 0; ct < 4; ++ct) {
#pragma unroll
      for (int j = 0; j < 4; ++j) {
        const int r = rb4 + j;
        if (r < N_NODES) p0u[(size_t)r * HID + ct * 16 + cc] = bf16rne(acc[ct][j]);
      }
    }
  } else {  // -> s0bu (bf16 + bias)
#pragma unroll
    for (int ct = 0; ct < 4; ++ct) {
      const float bias = b0[ct * 16 + cc];
#pragma unroll
      for (int j = 0; j < 4; ++j) {
        const int r = rb4 + j;
        if (r < N_NODES)
          s0bu[(size_t)r * HID + ct * 16 + cc] = bf16rne(acc[ct][j] + bias);
      }
    }
  }
}

// ---------- fuseA: part_count (blocks 0..499) || gemm0 colgrp0 --------------
__global__ __launch_bounds__(256) void fuseA(
    const float* __restrict__ x, const _Float16* __restrict__ B0f,
    const float* __restrict__ b0,
    unsigned short* __restrict__ p0u, unsigned short* __restrict__ s0bu,
    const int* __restrict__ w, const int* __restrict__ flag,
    int* __restrict__ blkbase) {
  __shared__ _Float16 lb[64 * 128];  // 16 KB (pc path: int hist scratch)
  const int tid = threadIdx.x;

  if (blockIdx.x < NPBLK) {
    int* h = (int*)lb;
    const int b = blockIdx.x;
    for (int i = tid; i < NBKT; i += 256) h[i] = 0;
    __syncthreads();
    const int i64 = flag[0];
    const int pEnd = (b + 1) * PAIRS_PER_BLK;
    for (int p = b * PAIRS_PER_BLK + tid; p < pEnd; p += 256) {
      int d0, d1;
      if (i64) {
        const int4 vd = *(const int4*)(w + 2 * (size_t)N_EDGES + 4 * (size_t)p);
        d0 = vd.x; d1 = vd.z;
      } else {
        const int2 vd = *(const int2*)(w + (size_t)N_EDGES + 2 * (size_t)p);
        d0 = vd.x; d1 = vd.y;
      }
      atomicAdd(&h[d0 >> 7], 1);
      atomicAdd(&h[d1 >> 7], 1);
    }
    __syncthreads();
    for (int i = tid; i < NBKT; i += 256)
      blkbase[(size_t)b * NBKT + i] = h[i];  // plain coalesced store
    return;
  }
  gemm0_body(blockIdx.x - NPBLK, 0, tid, lb, x, B0f, b0, p0u, s0bu);
}

// ---------- bscan: per-bucket cross-block exclusive scan (782 blocks) -------
__global__ __launch_bounds__(256) void bscan(int* __restrict__ blkbase,
                                             int* __restrict__ gcount) {
  __shared__ int lds[256];
  const int i = blockIdx.x;  // bucket
  const int t = threadIdx.x;
  const int v0 = (t < NPBLK) ? blkbase[(size_t)t * NBKT + i] : 0;
  const int v1 = (t + 256 < NPBLK) ? blkbase[(size_t)(t + 256) * NBKT + i] : 0;
  const int s = v0 + v1;
  lds[t] = s;
  __syncthreads();
  for (int o = 1; o < 256; o <<= 1) {
    const int val = (t >= o) ? lds[t - o] : 0;
    __syncthreads();
    lds[t] += val;
    __syncthreads();
  }
  const int run = lds[t] - s;
  if (t == 255) gcount[i] = lds[255];
  if (t < NPBLK) blkbase[(size_t)t * NBKT + i] = run;
  if (t + 256 < NPBLK) blkbase[(size_t)(t + 256) * NBKT + i] = run + v0;
}

// ---------- Phase B: single-block exclusive scan of 782 bucket counts -------
__global__ __launch_bounds__(256) void part_scan(
    const int* __restrict__ gcount, int* __restrict__ gbase) {
  __shared__ int lds[256];
  const int t = threadIdx.x;
  int v[4];
  int s = 0;
#pragma unroll
  for (int j = 0; j < 4; ++j) {
    const int idx = t * 4 + j;
    v[j] = (idx < NBKT) ? gcount[idx] : 0;
    s += v[j];
  }
  lds[t] = s;
  __syncthreads();
  for (int o = 1; o < 256; o <<= 1) {
    const int val = (t >= o) ? lds[t - o] : 0;
    __syncthreads();
    lds[t] += val;
    __syncthreads();
  }
  int run = lds[t] - s;
#pragma unroll
  for (int j = 0; j < 4; ++j) {
    const int idx = t * 4 + j;
    if (idx < NBKT) gbase[idx] = run;
    run += v[j];
  }
}

// ---------- fuseB: part_scatter (blocks 0..499) || gemm0 colgrp1 ------------
// pe[e] = src | (localdst << 17)   (src < 2^17, localdst < 128)
__global__ __launch_bounds__(256) void fuseB(
    const float* __restrict__ x, const _Float16* __restrict__ B0f,
    const float* __restrict__ b0,
    unsigned short* __restrict__ p0u, unsigned short* __restrict__ s0bu,
    const int* __restrict__ w, const int* __restrict__ flag,
    const int* __restrict__ gbase, const int* __restrict__ blkbase,
    int* __restrict__ pe) {
  __shared__ _Float16 lb[64 * 128];  // 16 KB (scatter path: cur[] scratch)
  const int tid = threadIdx.x;

  if (blockIdx.x < NPBLK) {
    int* cur = (int*)lb;
    const int t = tid, b = blockIdx.x;
    for (int i = t; i < NBKT; i += 256)
      cur[i] = gbase[i] + blkbase[(size_t)b * NBKT + i];
    __syncthreads();
    const int i64 = flag[0];
    const int pEnd = (b + 1) * PAIRS_PER_BLK;
    for (int p = b * PAIRS_PER_BLK + t; p < pEnd; p += 256) {
      int s0, s1, d0, d1;
      if (i64) {
        const int4 vs = *(const int4*)(w + 4 * (size_t)p);
        const int4 vd = *(const int4*)(w + 2 * (size_t)N_EDGES + 4 * (size_t)p);
        s0 = vs.x; s1 = vs.z;
        d0 = vd.x; d1 = vd.z;
      } else {
        const int2 vs = *(const int2*)(w + 2 * (size_t)p);
        const int2 vd = *(const int2*)(w + (size_t)N_EDGES + 2 * (size_t)p);
        s0 = vs.x; s1 = vs.y;
        d0 = vd.x; d1 = vd.y;
      }
      const int sl0 = atomicAdd(&cur[d0 >> 7], 1);
      pe[sl0] = s0 | ((d0 & 127) << 17);
      const int sl1 = atomicAdd(&cur[d1 >> 7], 1);
      pe[sl1] = s1 | ((d1 & 127) << 17);
    }
    return;
  }
  gemm0_body(blockIdx.x - NPBLK, 1, tid, lb, x, B0f, b0, p0u, s0bu);
}

// ---------- Phase D: per-bucket CSR build, padded to x4 with zero-row -------
__global__ __launch_bounds__(256) void bucket_csr(
    const int* __restrict__ pe, const int* __restrict__ gbase,
    const int* __restrict__ gcount, int* __restrict__ deg,
    int* __restrict__ off, int* __restrict__ sortedSrc) {
  __shared__ int ldeg[128];
  __shared__ int loff[128];
  __shared__ int lcur[128];
  const int t = threadIdx.x;
  const int bkt = blockIdx.x;
  const int nbase = bkt << 7;
  const int ebase = gbase[bkt];
  const int cnt = gcount[bkt];
  const int outbase = ebase + PADCAP * bkt;
  if (t < 128) ldeg[t] = 0;
  __syncthreads();
  for (int e = t; e < cnt; e += 256) {
    const int pv = pe[ebase + e];
    atomicAdd(&ldeg[(pv >> 17) & 127], 1);
  }
  __syncthreads();
  if (t < 128) loff[t] = (ldeg[t] + 3) & ~3;  // padded degree
  __syncthreads();
  for (int o = 1; o < 128; o <<= 1) {
    int v = 0;
    if (t >= o && t < 128) v = loff[t - o];
    __syncthreads();
    if (t < 128) loff[t] += v;
    __syncthreads();
  }
  if (t < 128) {
    const int pdeg = (ldeg[t] + 3) & ~3;
    const int ex = loff[t] - pdeg;
    lcur[t] = ex;
    const int n = nbase + t;
    if (n < N_NODES) {
      deg[n] = ldeg[t];
      off[n] = outbase + ex;
    }
  }
  __syncthreads();
  for (int e = t; e < cnt; e += 256) {
    const int pv = pe[ebase + e];
    const int ld = (pv >> 17) & 127;
    const int p = atomicAdd(&lcur[ld], 1);
    sortedSrc[outbase + p] = pv & 0x1FFFF;
  }
  __syncthreads();
  if (t < 128) {
    const int pdeg = (ldeg[t] + 3) & ~3;
    const int ex = loff[t] - pdeg;
    for (int q = ldeg[t]; q < pdeg; ++q)
      sortedSrc[outbase + ex + q] = N_NODES;  // zero row
  }
}

// ------- Layer 1 bf16 MFMA GEMM: [p1 | s1b] = h1 @ [Wn1 | Ws1] (+b1) --------
__global__ __launch_bounds__(256) void gemm1(
    const unsigned short* __restrict__ h1u, const unsigned short* __restrict__ B1u,
    const float* __restrict__ b1,
    unsigned short* __restrict__ p1u, unsigned short* __restrict__ s1bu) {
  __shared__ unsigned short lb[64 * 64];  // 8 KB
  const int tid = threadIdx.x;
  const int lane = tid & 63;
  const int wave = tid >> 6;
  const int rowbase = blockIdx.x * 64 + wave * 16;
  const int arow = rowbase + (lane & 15);
  const int rclamp = (arow < N_NODES) ? arow : 0;
  const int ko = (lane >> 4) << 3;

  short8 ah[2];
  {
    const unsigned short* ax = h1u + (size_t)rclamp * HID + ko;
    ah[0] = *(const short8*)ax;
    ah[1] = *(const short8*)(ax + 32);
  }
  {
    const uint4* gb = (const uint4*)B1u;
    for (int i = tid; i < 512; i += 256) {
      const int o = i << 4;
      const int sw = o ^ (((o >> 7) & 7) << 4);
      *(uint4*)((char*)lb + sw) = gb[i];
    }
  }
  __syncthreads();

  f32x4 acc[4];
#pragma unroll
  for (int ct = 0; ct < 4; ++ct) acc[ct] = (f32x4){0.f, 0.f, 0.f, 0.f};

#pragma unroll
  for (int ks = 0; ks < 2; ++ks) {
    const int kb = ks * 64 + (ko << 1);
#pragma unroll
    for (int ct = 0; ct < 4; ++ct) {
      const int n = ct * 16 + (lane & 15);
      const int boff = (n << 7) + kb;
      const int sb = boff ^ (((boff >> 7) & 7) << 4);
      const short8 bv = *(const short8*)((const char*)lb + sb);
      acc[ct] = __builtin_amdgcn_mfma_f32_16x16x32_bf16(ah[ks], bv, acc[ct], 0, 0, 0);
    }
  }
  const int rb4 = rowbase + ((lane >> 4) << 2);
  const int cc = lane & 15;
#pragma unroll
  for (int ct = 0; ct < 2; ++ct) {  // -> p1 (bf16)
#pragma unroll
    for (int j = 0; j < 4; ++j) {
      const int r = rb4 + j;
      if (r < N_NODES) p1u[(size_t)r * OUT_DIM + ct * 16 + cc] = bf16rne(acc[ct][j]);
    }
  }
#pragma unroll
  for (int ct = 2; ct < 4; ++ct) {  // -> s1bu (bf16 + bias)
#pragma unroll
    for (int j = 0; j < 4; ++j) {
      const int r = rb4 + j;
      if (r < N_NODES)
        s1bu[(size_t)r * OUT_DIM + (ct - 2) * 16 + cc] =
            bf16rne(acc[ct][j] + b1[(ct - 2) * 16 + cc]);
    }
  }
}

// ------- Fused layer-0 aggregate + mean + LN + ReLU -> h1u (2 nodes/wave) ---
__global__ __launch_bounds__(256) void aggc0(
    const int* __restrict__ sortedSrc, const int* __restrict__ off,
    const int* __restrict__ deg, const unsigned short* __restrict__ p0u,
    const unsigned short* __restrict__ s0bu, const float* __restrict__ g,
    const float* __restrict__ be, unsigned short* __restrict__ h1u) {
  const int lane = threadIdx.x & 63;
  const int h = lane >> 5;          // node half
  const int grp = (lane >> 3) & 3;  // 4 edge groups
  const int sl = lane & 7;          // 8 feature slices
  const int i = blockIdx.x * 8 + ((threadIdx.x >> 6) << 1) + h;
  const int st = off[i];
  const int dg = deg[i];
  const int dgp = (dg + 3) & ~3;
  const int dgmaxp = max(dgp, __shfl_xor(dgp, 32));
  float acc[8];
#pragma unroll
  for (int f = 0; f < 8; ++f) acc[f] = 0.f;

  for (int base = 0; base < dgmaxp; base += 32) {
    const int cntp = dgp - base;
    const int l5 = lane & 31;
    const int idx = (l5 < cntp) ? sortedSrc[st + base + l5] : N_NODES;
    const int cm = min(32, dgmaxp - base);  // multiple of 4
    for (int j = 0; j * 4 < cm; ++j) {
      const int e = j * 4 + grp;
      const int srcn = __shfl(idx, (h << 5) | e);
      const uint4 q = *(const uint4*)(p0u + (size_t)srcn * HID + sl * 8);
      acc[0] += uflo(q.x); acc[1] += ufhi(q.x);
      acc[2] += uflo(q.y); acc[3] += ufhi(q.y);
      acc[4] += uflo(q.z); acc[5] += ufhi(q.z);
      acc[6] += uflo(q.w); acc[7] += ufhi(q.w);
    }
  }
  // fold edge groups (xor over lane bits 3,4 — stays within node half)
#pragma unroll
  for (int mk = 8; mk < 32; mk <<= 1) {
#pragma unroll
    for (int f = 0; f < 8; ++f) acc[f] += __shfl_xor(acc[f], mk);
  }
  const float inv = 1.0f / fmaxf((float)dg, 1.0f);
  float z[8];
  const uint4 sbv = *(const uint4*)(s0bu + (size_t)i * HID + sl * 8);
  z[0] = uflo(sbv.x) + acc[0] * inv; z[1] = ufhi(sbv.x) + acc[1] * inv;
  z[2] = uflo(sbv.y) + acc[2] * inv; z[3] = ufhi(sbv.y) + acc[3] * inv;
  z[4] = uflo(sbv.z) + acc[4] * inv; z[5] = ufhi(sbv.z) + acc[5] * inv;
  z[6] = uflo(sbv.w) + acc[6] * inv; z[7] = ufhi(sbv.w) + acc[7] * inv;
  float pm = 0.f;
#pragma unroll
  for (int f = 0; f < 8; ++f) pm += z[f];
#pragma unroll
  for (int mk = 1; mk < 8; mk <<= 1) pm += __shfl_xor(pm, mk);
  const float mean = pm * (1.0f / 64.0f);
  float pv = 0.f;
#pragma unroll
  for (int f = 0; f < 8; ++f) {
    z[f] -= mean;
    pv += z[f] * z[f];
  }
#pragma unroll
  for (int mk = 1; mk < 8; mk <<= 1) pv += __shfl_xor(pv, mk);
  const float rstd = rsqrtf(pv * (1.0f / 64.0f) + LN_EPS);
  if (grp == 0) {
    const float4 gv0 = *(const float4*)(g + sl * 8);
    const float4 gv1 = *(const float4*)(g + sl * 8 + 4);
    const float4 bv0 = *(const float4*)(be + sl * 8);
    const float4 bv1 = *(const float4*)(be + sl * 8 + 4);
    uint4 ov;
    ov.x = pk(fmaxf(z[0] * rstd * gv0.x + bv0.x, 0.f),
              fmaxf(z[1] * rstd * gv0.y + bv0.y, 0.f));
    ov.y = pk(fmaxf(z[2] * rstd * gv0.z + bv0.z, 0.f),
              fmaxf(z[3] * rstd * gv0.w + bv0.w, 0.f));
    ov.z = pk(fmaxf(z[4] * rstd * gv1.x + bv1.x, 0.f),
              fmaxf(z[5] * rstd * gv1.y + bv1.y, 0.f));
    ov.w = pk(fmaxf(z[6] * rstd * gv1.z + bv1.z, 0.f),
              fmaxf(z[7] * rstd * gv1.w + bv1.w, 0.f));
    *(uint4*)(h1u + (size_t)i * HID + sl * 8) = ov;
  }
}

// ------- Fused layer-1 aggregate + mean + LN + ReLU -> out (4 nodes/wave) ---
__global__ __launch_bounds__(256) void aggc1(
    const int* __restrict__ sortedSrc, const int* __restrict__ off,
    const int* __restrict__ deg, const unsigned short* __restrict__ p1u,
    const unsigned short* __restrict__ s1bu, const float* __restrict__ g,
    const float* __restrict__ be, float* __restrict__ out) {
  const int lane = threadIdx.x & 63;
  const int q4 = lane >> 4;         // node quarter
  const int grp = (lane >> 2) & 3;  // 4 edge groups
  const int sl = lane & 3;          // 4 feature slices
  const int i = blockIdx.x * 16 + ((threadIdx.x >> 6) << 2) + q4;
  const int st = off[i];
  const int dg = deg[i];
  const int dgp = (dg + 3) & ~3;
  int dm = max(dgp, __shfl_xor(dgp, 16));
  const int dgmaxp = max(dm, __shfl_xor(dm, 32));
  float acc[8];
#pragma unroll
  for (int f = 0; f < 8; ++f) acc[f] = 0.f;

  for (int base = 0; base < dgmaxp; base += 16) {
    const int cntp = dgp - base;
    const int l4 = lane & 15;
    const int idx = (l4 < cntp) ? sortedSrc[st + base + l4] : N_NODES;
    const int cm = min(16, dgmaxp - base);  // multiple of 4
    for (int j = 0; j * 4 < cm; ++j) {
      const int e = j * 4 + grp;
      const int srcn = __shfl(idx, (q4 << 4) | e);
      const uint4 qv = *(const uint4*)(p1u + (size_t)srcn * OUT_DIM + sl * 8);
      acc[0] += uflo(qv.x); acc[1] += ufhi(qv.x);
      acc[2] += uflo(qv.y); acc[3] += ufhi(qv.y);
      acc[4] += uflo(qv.z); acc[5] += ufhi(qv.z);
      acc[6] += uflo(qv.w); acc[7] += ufhi(qv.w);
    }
  }
  // fold edge groups (xor over lane bits 2,3 — stays within node quarter)
#pragma unroll
  for (int mk = 4; mk < 16; mk <<= 1) {
#pragma unroll
    for (int f = 0; f < 8; ++f) acc[f] += __shfl_xor(acc[f], mk);
  }
  const float inv = 1.0f / fmaxf((float)dg, 1.0f);
  float z[8];
  const uint4 sbv = *(const uint4*)(s1bu + (size_t)i * OUT_DIM + sl * 8);
  z[0] = uflo(sbv.x) + acc[0] * inv; z[1] = ufhi(sbv.x) + acc[1] * inv;
  z[2] = uflo(sbv.y) + acc[2] * inv; z[3] = ufhi(sbv.y) + acc[3] * inv;
  z[4] = uflo(sbv.z) + acc[4] * inv; z[5] = ufhi(sbv.z) + acc[5] * inv;
  z[6] = uflo(sbv.w) + acc[6] * inv; z[7] = ufhi(sbv.w) + acc[7] * inv;
  float pm = 0.f;
#pragma unroll
  for (int f = 0; f < 8; ++f) pm += z[f];
#pragma unroll
  for (int mk = 1; mk < 4; mk <<= 1) pm += __shfl_xor(pm, mk);
  const float mean = pm * (1.0f / 32.0f);
  float pv = 0.f;
#pragma unroll
  for (int f = 0; f < 8; ++f) {
    z[f] -= mean;
    pv += z[f] * z[f];
  }
#pragma unroll
  for (int mk = 1; mk < 4; mk <<= 1) pv += __shfl_xor(pv, mk);
  const float rstd = rsqrtf(pv * (1.0f / 32.0f) + LN_EPS);
  if (grp == 0) {
    const float4 gv0 = *(const float4*)(g + sl * 8);
    const float4 gv1 = *(const float4*)(g + sl * 8 + 4);
    const float4 bv0 = *(const float4*)(be + sl * 8);
    const float4 bv1 = *(const float4*)(be + sl * 8 + 4);
    float4 o0, o1;
    o0.x = fmaxf(z[0] * rstd * gv0.x + bv0.x, 0.f);
    o0.y = fmaxf(z[1] * rstd * gv0.y + bv0.y, 0.f);
    o0.z = fmaxf(z[2] * rstd * gv0.z + bv0.z, 0.f);
    o0.w = fmaxf(z[3] * rstd * gv0.w + bv0.w, 0.f);
    o1.x = fmaxf(z[4] * rstd * gv1.x + bv1.x, 0.f);
    o1.y = fmaxf(z[5] * rstd * gv1.y + bv1.y, 0.f);
    o1.z = fmaxf(z[6] * rstd * gv1.z + bv1.z, 0.f);
    o1.w = fmaxf(z[7] * rstd * gv1.w + bv1.w, 0.f);
    *(float4*)(out + (size_t)i * OUT_DIM + sl * 8) = o0;
    *(float4*)(out + (size_t)i * OUT_DIM + sl * 8 + 4) = o1;
  }
}

extern "C" void kernel_launch(void* const* d_in, const int* in_sizes, int n_in,
                              void* d_out, int out_size, void* d_ws, size_t ws_size,
                              hipStream_t stream) {
  const float* x       = (const float*)d_in[0];
  const int*   edges   = (const int*)d_in[1];
  const float* Wself0  = (const float*)d_in[2];
  const float* Wneigh0 = (const float*)d_in[3];
  const float* b0      = (const float*)d_in[4];
  const float* g0      = (const float*)d_in[5];
  const float* be0     = (const float*)d_in[6];
  const float* Wself1  = (const float*)d_in[7];
  const float* Wneigh1 = (const float*)d_in[8];
  const float* b1      = (const float*)d_in[9];
  const float* g1      = (const float*)d_in[10];
  const float* be1     = (const float*)d_in[11];

  // ---- 256-byte-aligned workspace carve-out ----
  char* base = (char*)d_ws;
  size_t o = 0;
  auto carve = [&](size_t bytes) {
    char* p = base + o;
    o += (bytes + 255) & ~(size_t)255;
    return p;
  };
  int* flag      = (int*)carve(64 * 4);
  int* gcount    = (int*)carve(1024 * 4);
  int* gbase     = (int*)carve(1024 * 4);
  int* blkbase   = (int*)carve((size_t)NPBLK * NBKT * 4);
  int* deg       = (int*)carve((size_t)N_NODES * 4);
  int* off       = (int*)carve((size_t)N_NODES * 4);
  int* sortedSrc = (int*)carve(1950000 * 4);  // 1.6M + PADCAP*NBKT
  int* pe        = (int*)carve(6500000);      // 1.62M ints; later p1u overlay
  _Float16* B0f  = (_Float16*)carve(128 * 128 * 2);
  unsigned short* B1u = (unsigned short*)carve(64 * 64 * 2);
  unsigned short* p0u = (unsigned short*)carve(((size_t)N_NODES + 2) * HID * 2);
  unsigned short* s0bu = (unsigned short*)carve(((size_t)N_NODES + 2) * HID * 2);
  unsigned short* h1u = (unsigned short*)carve(((size_t)N_NODES + 2) * HID * 2);
  unsigned short* p1u = (unsigned short*)pe;   // overlay (pe dead after csr)
  unsigned short* s1bu = s0bu;                 // overlay (s0bu dead after aggc0)

  detect_edges<<<1, 256, 0, stream>>>(edges, flag, p0u, p1u);
  convW<<<80, 256, 0, stream>>>(Wneigh0, Wself0, Wneigh1, Wself1, B0f, B1u);
  fuseA<<<NPBLK + G0T, 256, 0, stream>>>(x, B0f, b0, p0u, s0bu,
                                         edges, flag, blkbase);
  bscan<<<NBKT, 256, 0, stream>>>(blkbase, gcount);
  part_scan<<<1, 256, 0, stream>>>(gcount, gbase);
  fuseB<<<NPBLK + G0T, 256, 0, stream>>>(x, B0f, b0, p0u, s0bu,
                                         edges, flag, gbase, blkbase, pe);
  bucket_csr<<<NBKT, 256, 0, stream>>>(pe, gbase, gcount, deg, off, sortedSrc);

  aggc0<<<N_NODES / 8, 256, 0, stream>>>(sortedSrc, off, deg, p0u, s0bu,
                                         g0, be0, h1u);
  gemm1<<<(N_NODES + 63) / 64, 256, 0, stream>>>(h1u, B1u, b1, p1u, s1bu);
  aggc1<<<N_NODES / 16, 256, 0, stream>>>(sortedSrc, off, deg, p1u, s1bu,
                                          g1, be1, (float*)d_out);
}